// Round 7
// baseline (2292.391 us; speedup 1.0000x reference)
//
#include <hip/hip_runtime.h>
#include <math.h>

#define N_NODES 50000
#define E_EDGES 1600000
#define IN_CH   34
#define NEG     0.2f
#define NB      196          // coarse buckets: dst>>8
#define CAP     10000        // bucket capacity (E[8192], sigma~90)

typedef __attribute__((ext_vector_type(2))) float fv2;

static __device__ __forceinline__ unsigned short f2bf(float f) {
    unsigned int u = __float_as_uint(f);
    u += 0x7fffu + ((u >> 16) & 1u);
    return (unsigned short)(u >> 16);
}
static __device__ __forceinline__ float bflo(unsigned int u) {
    return __uint_as_float(u << 16);
}
static __device__ __forceinline__ float bfhi(unsigned int u) {
    return __uint_as_float(u & 0xffff0000u);
}
static __device__ __forceinline__ float lrelu_exp(float e) {
    return expf(e > 0.f ? e : NEG * e);
}

// Exclusive scan over 256 values held by the first 256 threads of a
// 1024-thread block. ALL 1024 threads must call (contains barriers).
static __device__ __forceinline__ int scan256_1024(int v, int* wsum) {
    const int lane = threadIdx.x & 63, wv = threadIdx.x >> 6;
    int x = v;
    #pragma unroll
    for (int off = 1; off < 64; off <<= 1) {
        int y = __shfl_up(x, off);
        if (lane >= off) x += y;
    }
    if (wv < 4 && lane == 63) wsum[wv] = x;
    __syncthreads();
    if (threadIdx.x < 4) {
        int s = wsum[threadIdx.x];
        #pragma unroll
        for (int off = 1; off < 4; off <<= 1) {
            int y = __shfl_up(s, off);
            if ((int)threadIdx.x >= off) s += y;
        }
        wsum[threadIdx.x] = s;
    }
    __syncthreads();
    const int woff = (wv >= 1 && wv < 4) ? wsum[wv - 1] : 0;
    return woff + x - v;
}

// ---------------------------------------------------------------------------
// Coarse binning: 196 blocks x 1024 threads. LDS-staged raw+ebuf; coalesced
// bucket-run writes to bucket-strided `binned`. gcur zeroed beforehand.
// ---------------------------------------------------------------------------
__global__ __launch_bounds__(1024) void k_bin(
    const int* __restrict__ srcA, const int* __restrict__ dstA,
    int* __restrict__ gcur, unsigned int* __restrict__ binned)
{
    __shared__ unsigned int raw[8192];    // 32 KB
    __shared__ unsigned int ebuf[8192];   // 32 KB
    __shared__ int cnt[256], loff[256], lcur[256], cur[256];
    __shared__ int wsum[4];
    const int tid = threadIdx.x;
    const int base = blockIdx.x * 8192;
    const int mE = min(8192, E_EDGES - base);   // %4 == 0
    const int nq = mE >> 2;
    if (tid < 256) cnt[tid] = 0;
    __syncthreads();
    for (int q = tid; q < nq; q += 1024) {
        const int4 d4 = ((const int4*)(dstA + base))[q];
        const int4 s4 = ((const int4*)(srcA + base))[q];
        raw[4 * q + 0] = ((unsigned)d4.x << 16) | (unsigned)s4.x;
        raw[4 * q + 1] = ((unsigned)d4.y << 16) | (unsigned)s4.y;
        raw[4 * q + 2] = ((unsigned)d4.z << 16) | (unsigned)s4.z;
        raw[4 * q + 3] = ((unsigned)d4.w << 16) | (unsigned)s4.w;
        atomicAdd(&cnt[d4.x >> 8], 1);
        atomicAdd(&cnt[d4.y >> 8], 1);
        atomicAdd(&cnt[d4.z >> 8], 1);
        atomicAdd(&cnt[d4.w >> 8], 1);
    }
    __syncthreads();
    const int v = (tid < 256) ? cnt[tid] : 0;
    const int excl = scan256_1024(v, wsum);
    if (tid < 256) { loff[tid] = excl; lcur[tid] = excl; }
    if (tid < NB) cur[tid] = (v > 0) ? (tid * CAP + atomicAdd(&gcur[tid], v)) : 0;
    __syncthreads();
    for (int p = tid; p < mE; p += 1024) {
        const unsigned int u = raw[p];
        const int q = atomicAdd(&lcur[u >> 24], 1);
        ebuf[q] = u;
    }
    __syncthreads();
    for (int p = tid; p < mE; p += 1024) {
        const unsigned int u = ebuf[p];
        const int b = (int)(u >> 24);
        binned[cur[b] + (p - loff[b])] = u;
    }
}

// ---------------------------------------------------------------------------
// Layer 1 node GEMM, standalone 256 threads: xw1b = bf16(x @ W1), logits.
// ---------------------------------------------------------------------------
__global__ __launch_bounds__(256) void k_node1(
    const float* __restrict__ x, const float* __restrict__ W1,
    const float* __restrict__ a_src, const float* __restrict__ a_dst,
    unsigned short* __restrict__ xw1b,
    float* __restrict__ al_s, float* __restrict__ al_d)
{
    __shared__ float sW[IN_CH * 132];        // 17952 B
    __shared__ float sx[32 * 35];            // 4480 B
    __shared__ float sas[128], sad[128];
    const int tid = threadIdx.x;
    for (int i = tid; i < IN_CH * 128; i += 256) {
        int k = i >> 7, c = i & 127;
        sW[k * 132 + c] = W1[i];
    }
    if (tid < 128) { sas[tid] = a_src[tid]; sad[tid] = a_dst[tid]; }
    const int n0 = blockIdx.x * 32;
    for (int i = tid; i < 32 * IN_CH; i += 256) {
        int n = i / IN_CH;
        sx[n * 35 + (i - n * IN_CH)] = (n0 + n < N_NODES) ? x[n0 * IN_CH + i] : 0.f;
    }
    __syncthreads();

    const int tc = tid & 31, tn = tid >> 5;
    float acc[4][4] = {{0.f}};
    for (int k = 0; k < IN_CH; ++k) {
        const float4 wv = *reinterpret_cast<const float4*>(&sW[k * 132 + 4 * tc]);
        #pragma unroll
        for (int j = 0; j < 4; ++j) {
            const float hj = sx[(4 * tn + j) * 35 + k];
            acc[j][0] += hj * wv.x; acc[j][1] += hj * wv.y;
            acc[j][2] += hj * wv.z; acc[j][3] += hj * wv.w;
        }
    }
    #pragma unroll
    for (int j = 0; j < 4; ++j) {
        const int node = n0 + 4 * tn + j;
        float ps = 0.f, pd = 0.f;
        #pragma unroll
        for (int c = 0; c < 4; ++c) {
            ps += acc[j][c] * sas[4 * tc + c];
            pd += acc[j][c] * sad[4 * tc + c];
        }
        #pragma unroll
        for (int off = 1; off < 16; off <<= 1) {
            ps += __shfl_xor(ps, off);
            pd += __shfl_xor(pd, off);
        }
        if (node < N_NODES) {
            if ((tc & 15) == 0) {
                int h = tc >> 4;
                al_s[node * 2 + h] = ps;
                al_d[node * 2 + h] = pd;
            }
            ushort4 u;
            u.x = f2bf(acc[j][0]); u.y = f2bf(acc[j][1]);
            u.z = f2bf(acc[j][2]); u.w = f2bf(acc[j][3]);
            *reinterpret_cast<ushort4*>(&xw1b[node * 128 + 4 * tc]) = u;
        }
    }
}

// ---------------------------------------------------------------------------
// Layer 1 gather-accumulate: one block per bucket (256 dst nodes), all 256
// accumulators live in LDS (128 KB). No per-node edge ordering needed —
// the softmax division is deferred to the epilogue:
//   out[n] = (w_self*x[n] + sum_e w_e*x[src_e]) / (w_self + sum_e w_e).
// Per 64-edge chunk per wave: phase A computes per-edge weights (staged in
// per-wave LDS, same ordering idiom as the proven AB staging), phase B does
// 1 row fetch + pk_mul + 2 ds_add_f32 per lane per edge.
// ---------------------------------------------------------------------------
__global__ __launch_bounds__(1024) void k_gacc1(
    const int* __restrict__ gcur, const unsigned int* __restrict__ binned,
    const unsigned int* __restrict__ xw1u,    // 64 uints per row
    const float* __restrict__ al_s, const float* __restrict__ al_d,
    const float* __restrict__ b1, float* __restrict__ hbuf)
{
    __shared__ float accum[256 * 128];        // 128 KB
    __shared__ float den0[256], den1[256];    // 2 KB
    __shared__ __align__(16) float4 wstage[16][64];  // 16 KB  (total 149.5 KB)
    const int tid = threadIdx.x;
    const int wave = tid >> 6, lane = tid & 63;
    const int head = lane >> 5;
    const int b = blockIdx.x;
    const int n0 = b * 256;
    const int bbase = b * CAP;
    const int cntb = gcur[b];

    // init denominators with the self-loop weight
    for (int i = tid; i < 256; i += 1024) {
        const int node = n0 + i;
        if (node < N_NODES) {
            const float2 als = *reinterpret_cast<const float2*>(&al_s[node * 2]);
            const float2 ald = *reinterpret_cast<const float2*>(&al_d[node * 2]);
            den0[i] = lrelu_exp(als.x + ald.x);
            den1[i] = lrelu_exp(als.y + ald.y);
        }
    }
    __syncthreads();
    // init accumulators with the self-loop term
    #pragma unroll 1
    for (int j = 0; j < 16; ++j) {
        const int i = wave * 16 + j;
        const int node = n0 + i;
        if (node < N_NODES) {
            const unsigned int su = xw1u[node * 64 + lane];
            const float ws = head ? den1[i] : den0[i];
            accum[i * 128 + 2 * lane]     = ws * bflo(su);
            accum[i * 128 + 2 * lane + 1] = ws * bfhi(su);
        }
    }
    __syncthreads();

    // main: 64-edge chunks per wave
    for (int basee = wave * 64; basee < cntb; basee += 1024) {
        const int m = min(64, cntb - basee);
        if (lane < m) {
            const unsigned int u = binned[bbase + basee + lane];
            const int s  = (int)(u & 0xffffu);
            const int d8 = (int)((u >> 16) & 255u);
            const float2 als = *reinterpret_cast<const float2*>(&al_s[s * 2]);
            const float2 ald = *reinterpret_cast<const float2*>(&al_d[(n0 + d8) * 2]);
            const float w0 = lrelu_exp(als.x + ald.x);
            const float w1 = lrelu_exp(als.y + ald.y);
            atomicAdd(&den0[d8], w0);
            atomicAdd(&den1[d8], w1);
            wstage[wave][lane] = make_float4(__int_as_float(s << 6), w0, w1,
                                             __int_as_float(d8 << 7));
        }
        int p = 0;
        for (; p + 4 <= m; p += 4) {
            const float4 q0 = wstage[wave][p + 0];
            const float4 q1 = wstage[wave][p + 1];
            const float4 q2 = wstage[wave][p + 2];
            const float4 q3 = wstage[wave][p + 3];
            const unsigned int r0 = xw1u[__float_as_int(q0.x) + lane];
            const unsigned int r1 = xw1u[__float_as_int(q1.x) + lane];
            const unsigned int r2 = xw1u[__float_as_int(q2.x) + lane];
            const unsigned int r3 = xw1u[__float_as_int(q3.x) + lane];
            float w; int a;
            w = head ? q0.z : q0.y; a = __float_as_int(q0.w) + 2 * lane;
            atomicAdd(&accum[a], w * bflo(r0)); atomicAdd(&accum[a + 1], w * bfhi(r0));
            w = head ? q1.z : q1.y; a = __float_as_int(q1.w) + 2 * lane;
            atomicAdd(&accum[a], w * bflo(r1)); atomicAdd(&accum[a + 1], w * bfhi(r1));
            w = head ? q2.z : q2.y; a = __float_as_int(q2.w) + 2 * lane;
            atomicAdd(&accum[a], w * bflo(r2)); atomicAdd(&accum[a + 1], w * bfhi(r2));
            w = head ? q3.z : q3.y; a = __float_as_int(q3.w) + 2 * lane;
            atomicAdd(&accum[a], w * bflo(r3)); atomicAdd(&accum[a + 1], w * bfhi(r3));
        }
        for (; p < m; ++p) {
            const float4 q = wstage[wave][p];
            const unsigned int r = xw1u[__float_as_int(q.x) + lane];
            const float w = head ? q.z : q.y;
            const int a = __float_as_int(q.w) + 2 * lane;
            atomicAdd(&accum[a], w * bflo(r)); atomicAdd(&accum[a + 1], w * bfhi(r));
        }
    }
    __syncthreads();

    // epilogue: divide + bias + relu, coalesced write
    const float2 bv = *reinterpret_cast<const float2*>(&b1[2 * lane]);
    #pragma unroll 1
    for (int j = 0; j < 16; ++j) {
        const int i = wave * 16 + j;
        const int node = n0 + i;
        if (node < N_NODES) {
            const float d = head ? den1[i] : den0[i];
            float o0 = accum[i * 128 + 2 * lane] / d + bv.x;
            float o1 = accum[i * 128 + 2 * lane + 1] / d + bv.y;
            o0 = o0 > 0.f ? o0 : 0.f;
            o1 = o1 > 0.f ? o1 : 0.f;
            *reinterpret_cast<float2*>(&hbuf[node * 128 + 2 * lane]) =
                make_float2(o0, o1);
        }
    }
}

// ---------------------------------------------------------------------------
// Layer 2 node pre-pass (register-tiled): xw2b = bf16(h @ W2) [N,64].
// ---------------------------------------------------------------------------
__global__ __launch_bounds__(256) void k_node2(
    const float* __restrict__ hbuf, const float* __restrict__ W2,
    const float* __restrict__ a_src, const float* __restrict__ a_dst,
    unsigned short* __restrict__ xw2b, float* __restrict__ al_s, float* __restrict__ al_d)
{
    __shared__ float sW[128 * 64];
    __shared__ float sh[64 * 129];
    __shared__ float sas[64], sad[64];
    const int tid = threadIdx.x;
    for (int i = tid; i < 128 * 64; i += 256) sW[i] = W2[i];
    if (tid < 64) { sas[tid] = a_src[tid]; sad[tid] = a_dst[tid]; }
    const int n0 = blockIdx.x * 64;
    for (int i = tid; i < 64 * 128; i += 256) {
        int n = i >> 7, c = i & 127;
        sh[n * 129 + c] = (n0 + n < N_NODES) ? hbuf[(long)(n0 + n) * 128 + c] : 0.f;
    }
    __syncthreads();

    const int tc = tid & 15, tn = tid >> 4;
    float acc[4][4] = {{0.f}};
    for (int k = 0; k < 128; ++k) {
        const float4 wv = *reinterpret_cast<const float4*>(&sW[k * 64 + 4 * tc]);
        #pragma unroll
        for (int j = 0; j < 4; ++j) {
            const float hj = sh[(4 * tn + j) * 129 + k];
            acc[j][0] += hj * wv.x; acc[j][1] += hj * wv.y;
            acc[j][2] += hj * wv.z; acc[j][3] += hj * wv.w;
        }
    }
    #pragma unroll
    for (int j = 0; j < 4; ++j) {
        const int node = n0 + 4 * tn + j;
        float ps = 0.f, pd = 0.f;
        #pragma unroll
        for (int c = 0; c < 4; ++c) {
            ps += acc[j][c] * sas[4 * tc + c];
            pd += acc[j][c] * sad[4 * tc + c];
        }
        #pragma unroll
        for (int off = 1; off < 16; off <<= 1) {
            ps += __shfl_xor(ps, off);
            pd += __shfl_xor(pd, off);
        }
        if (node < N_NODES) {
            if (tc == 0) { al_s[node] = ps; al_d[node] = pd; }
            ushort4 u;
            u.x = f2bf(acc[j][0]); u.y = f2bf(acc[j][1]);
            u.z = f2bf(acc[j][2]); u.w = f2bf(acc[j][3]);
            *reinterpret_cast<ushort4*>(&xw2b[node * 64 + 4 * tc]) = u;
        }
    }
}

// ---------------------------------------------------------------------------
// Layer 2 gather-accumulate: one block per bucket; 64 KB LDS accumulators;
// half-wave per edge (lane li owns cols 2li,2li+1), 2 edges per step.
// Single head: den[256] only.
// ---------------------------------------------------------------------------
__global__ __launch_bounds__(1024) void k_gacc2(
    const int* __restrict__ gcur, const unsigned int* __restrict__ binned,
    const unsigned int* __restrict__ xw2u,    // 32 uints per row
    const float* __restrict__ al_s, const float* __restrict__ al_d,
    const float* __restrict__ b2, float* __restrict__ out)
{
    __shared__ float accum[256 * 64];         // 64 KB
    __shared__ float den[256];                // 1 KB
    __shared__ __align__(8) float2 wstage[16][64];   // 8 KB
    const int tid = threadIdx.x;
    const int wave = tid >> 6, lane = tid & 63;
    const int li = lane & 31, hsel = lane >> 5;
    const int b = blockIdx.x;
    const int n0 = b * 256;
    const int bbase = b * CAP;
    const int cntb = gcur[b];

    for (int i = tid; i < 256; i += 1024) {
        const int node = n0 + i;
        if (node < N_NODES) den[i] = lrelu_exp(al_s[node] + al_d[node]);
    }
    __syncthreads();
    #pragma unroll 1
    for (int j = 0; j < 16; ++j) {
        const int i = wave * 16 + j;
        const int node = n0 + i;
        if (node < N_NODES && hsel == 0) {
            const unsigned int su = xw2u[node * 32 + li];
            const float ws = den[i];
            accum[i * 64 + 2 * li]     = ws * bflo(su);
            accum[i * 64 + 2 * li + 1] = ws * bfhi(su);
        }
    }
    __syncthreads();

    for (int basee = wave * 64; basee < cntb; basee += 1024) {
        const int m = min(64, cntb - basee);
        const int mp = (m + 1) & ~1;
        if (lane < m) {
            const unsigned int u = binned[bbase + basee + lane];
            const int s  = (int)(u & 0xffffu);
            const int d8 = (int)((u >> 16) & 255u);
            const float w = lrelu_exp(al_s[s] + al_d[n0 + d8]);
            atomicAdd(&den[d8], w);
            wstage[wave][lane] = make_float2(__int_as_float((s << 8) | d8), w);
        } else if (lane < mp) {
            wstage[wave][lane] = make_float2(__int_as_float(n0 << 8), 0.f);
        }
        int p = hsel;
        for (; p + 2 < mp; p += 4) {
            const float2 qa = wstage[wave][p];
            const float2 qb = wstage[wave][p + 2];
            const int pka = __float_as_int(qa.x);
            const int pkb = __float_as_int(qb.x);
            const unsigned int ra = xw2u[((pka >> 8) << 5) + li];
            const unsigned int rb = xw2u[((pkb >> 8) << 5) + li];
            const int aa = ((pka & 255) << 6) + 2 * li;
            const int ab = ((pkb & 255) << 6) + 2 * li;
            atomicAdd(&accum[aa], qa.y * bflo(ra));
            atomicAdd(&accum[aa + 1], qa.y * bfhi(ra));
            atomicAdd(&accum[ab], qb.y * bflo(rb));
            atomicAdd(&accum[ab + 1], qb.y * bfhi(rb));
        }
        for (; p < mp; p += 2) {
            const float2 q = wstage[wave][p];
            const int pk = __float_as_int(q.x);
            const unsigned int r = xw2u[((pk >> 8) << 5) + li];
            const int a = ((pk & 255) << 6) + 2 * li;
            atomicAdd(&accum[a], q.y * bflo(r));
            atomicAdd(&accum[a + 1], q.y * bfhi(r));
        }
    }
    __syncthreads();

    const float2 bv = *reinterpret_cast<const float2*>(&b2[2 * li]);
    #pragma unroll 1
    for (int j = 0; j < 16; ++j) {
        const int i = wave * 16 + j;
        const int node = n0 + i;
        if (node < N_NODES && hsel == 0) {
            const float d = den[i];
            const float o0 = accum[i * 64 + 2 * li] / d + bv.x;
            const float o1 = accum[i * 64 + 2 * li + 1] / d + bv.y;
            *reinterpret_cast<float2*>(&out[node * 64 + 2 * li]) =
                make_float2(o0, o1);
        }
    }
}

extern "C" void kernel_launch(void* const* d_in, const int* in_sizes, int n_in,
                              void* d_out, int out_size, void* d_ws, size_t ws_size,
                              hipStream_t stream)
{
    const float* x   = (const float*)d_in[0];
    const int*   ei  = (const int*)d_in[1];
    const float* W1  = (const float*)d_in[2];
    const float* as1 = (const float*)d_in[3];
    const float* ad1 = (const float*)d_in[4];
    const float* b1  = (const float*)d_in[5];
    const float* W2  = (const float*)d_in[6];
    const float* as2 = (const float*)d_in[7];
    const float* ad2 = (const float*)d_in[8];
    const float* b2  = (const float*)d_in[9];
    float* out = (float*)d_out;

    const int* srcA = ei;
    const int* dstA = ei + E_EDGES;

    // Workspace layout (bytes). Total 53,841,664 B (binned stays live through
    // gacc2 — no aliasing with hbuf anymore).
    char* ws = (char*)d_ws;
    unsigned int* binned = (unsigned int*)(ws);              // 7.84 MB
    int*   gcur       = (int*)(ws + 7840000);                // 784 B (pad 1024)
    float* al_s1      = (float*)(ws + 7841024);              // 400 KB (pad 400,128)
    float* al_d1      = (float*)(ws + 8241152);              // 400 KB
    float* al_s2      = (float*)(ws + 8641280);              // 200 KB (pad 200,192)
    float* al_d2      = (float*)(ws + 8841472);              // 200 KB
    unsigned short* xw1b = (unsigned short*)(ws + 9041664);  // 12.8 MB bf16
    float* hbuf       = (float*)(ws + 21841664);             // 25.6 MB fp32
    unsigned short* xw2b = (unsigned short*)(ws + 47441664); // 6.4 MB bf16

    hipMemsetAsync(gcur, 0, NB * sizeof(int), stream);
    hipLaunchKernelGGL(k_bin, dim3(NB), dim3(1024), 0, stream,
                       srcA, dstA, gcur, binned);
    hipLaunchKernelGGL(k_node1, dim3((N_NODES + 31) / 32), dim3(256), 0, stream,
                       x, W1, as1, ad1, xw1b, al_s1, al_d1);
    hipLaunchKernelGGL(k_gacc1, dim3(NB), dim3(1024), 0, stream,
                       gcur, binned, (const unsigned int*)xw1b,
                       al_s1, al_d1, b1, hbuf);
    hipLaunchKernelGGL(k_node2, dim3((N_NODES + 63) / 64), dim3(256), 0, stream,
                       hbuf, W2, as2, ad2, xw2b, al_s2, al_d2);
    hipLaunchKernelGGL(k_gacc2, dim3(NB), dim3(1024), 0, stream,
                       gcur, binned, (const unsigned int*)xw2b,
                       al_s2, al_d2, b2, out);
}

// Round 8
// 276.371 us; speedup vs baseline: 8.2946x; 8.2946x over previous
//
#include <hip/hip_runtime.h>
#include <math.h>

#define N_NODES 50000
#define E_EDGES 1600000
#define IN_CH   34
#define NEG     0.2f
#define NB      196          // coarse buckets: dst>>8
#define CAP     10000        // bucket capacity (E[8192], sigma~90)

typedef __attribute__((ext_vector_type(2))) float fv2;

static __device__ __forceinline__ unsigned short f2bf(float f) {
    unsigned int u = __float_as_uint(f);
    u += 0x7fffu + ((u >> 16) & 1u);
    return (unsigned short)(u >> 16);
}
static __device__ __forceinline__ float bflo(unsigned int u) {
    return __uint_as_float(u << 16);
}
static __device__ __forceinline__ float bfhi(unsigned int u) {
    return __uint_as_float(u & 0xffff0000u);
}
static __device__ __forceinline__ float lrelu_exp(float e) {
    return expf(e > 0.f ? e : NEG * e);
}

// Group same-key lanes of the wave (8-bit key). Returns mask of valid lanes
// sharing this lane's key. Must be called by all 64 lanes (contains ballots).
static __device__ __forceinline__ unsigned long long grp8(int key, bool valid) {
    unsigned long long m = __ballot(valid);
    #pragma unroll
    for (int b = 0; b < 8; ++b) {
        const unsigned long long bal = __ballot(key & (1 << b));
        m &= (key & (1 << b)) ? bal : ~bal;
    }
    return m;
}

// Exclusive scan over 256 values held by the first 256 threads of a
// 1024-thread block. ALL 1024 threads must call (contains barriers).
static __device__ __forceinline__ int scan256_1024(int v, int* wsum) {
    const int lane = threadIdx.x & 63, wv = threadIdx.x >> 6;
    int x = v;
    #pragma unroll
    for (int off = 1; off < 64; off <<= 1) {
        int y = __shfl_up(x, off);
        if (lane >= off) x += y;
    }
    if (wv < 4 && lane == 63) wsum[wv] = x;
    __syncthreads();
    if (threadIdx.x < 4) {
        int s = wsum[threadIdx.x];
        #pragma unroll
        for (int off = 1; off < 4; off <<= 1) {
            int y = __shfl_up(s, off);
            if ((int)threadIdx.x >= off) s += y;
        }
        wsum[threadIdx.x] = s;
    }
    __syncthreads();
    const int woff = (wv >= 1 && wv < 4) ? wsum[wv - 1] : 0;
    return woff + x - v;
}

// ---------------------------------------------------------------------------
// Coarse binning, ATOMIC-FREE: 196 blocks x 1024 threads. Ballot-rank
// counting sort (LDS atomic RMW unit measured at ~208 cyc/wave-instr in r7 —
// per-wave private counters + ballot groups avoid it entirely).
// gcur zeroed beforehand.
// ---------------------------------------------------------------------------
__global__ __launch_bounds__(1024) void k_bin(
    const int* __restrict__ srcA, const int* __restrict__ dstA,
    int* __restrict__ gcur, unsigned int* __restrict__ binned)
{
    __shared__ unsigned int raw[8192];     // 32 KB
    __shared__ unsigned int ebuf[8192];    // 32 KB
    __shared__ int pcnt[16][256];          // 16 KB: per-wave counts -> cursors
    __shared__ int loff[256], cur[256];
    __shared__ int wsum[4];
    const int tid = threadIdx.x;
    const int wave = tid >> 6, lane = tid & 63;
    const unsigned long long below = (1ull << lane) - 1ull;
    const int base = blockIdx.x * 8192;
    const int mE = min(8192, E_EDGES - base);

    for (int i = tid; i < 16 * 256; i += 1024) ((int*)pcnt)[i] = 0;
    __syncthreads();

    // P1: stage + per-wave ballot histogram (leader does plain LDS RMW)
    for (int c = wave; c < 128; c += 16) {
        const int idx = c * 64 + lane;
        const bool valid = idx < mE;
        unsigned int u = 0;
        if (valid) {
            const int d = dstA[base + idx], s = srcA[base + idx];
            u = ((unsigned)d << 16) | (unsigned)s;
            raw[idx] = u;
        }
        const int key = (int)(u >> 24);
        const unsigned long long m = grp8(key, valid);
        if (valid && (m & below) == 0ull)
            pcnt[wave][key] += (int)__popcll(m);
    }
    __syncthreads();

    // P2: per-key wave-prefix + block scan + global bucket cursors
    int run = 0;
    if (tid < 256) {
        #pragma unroll 1
        for (int w = 0; w < 16; ++w) {
            const int t = pcnt[w][tid];
            pcnt[w][tid] = run;
            run += t;
        }
    }
    const int excl = scan256_1024(run, wsum);
    if (tid < 256) loff[tid] = excl;
    if (tid < NB) cur[tid] = (run > 0) ? (tid * CAP + atomicAdd(&gcur[tid], run)) : 0;
    __syncthreads();
    if (tid < 256) {
        #pragma unroll 1
        for (int w = 0; w < 16; ++w) pcnt[w][tid] += excl;
    }
    __syncthreads();

    // P3: rank-based scatter into block-sorted ebuf (no atomics)
    for (int c = wave; c < 128; c += 16) {
        const int idx = c * 64 + lane;
        const bool valid = idx < mE;
        const unsigned int u = valid ? raw[idx] : 0u;
        const int key = (int)(u >> 24);
        const unsigned long long m = grp8(key, valid);
        const int rank = (int)__popcll(m & below);
        const int leader = valid ? (__ffsll((long long)m) - 1) : 0;
        int basep = 0;
        if (valid && rank == 0) basep = pcnt[wave][key];
        basep = __shfl(basep, leader);
        if (valid) {
            ebuf[basep + rank] = u;
            if (rank == 0) pcnt[wave][key] = basep + (int)__popcll(m);
        }
    }
    __syncthreads();

    // P4: linear LDS read -> coalesced bucket-run writes
    for (int p = tid; p < mE; p += 1024) {
        const unsigned int u = ebuf[p];
        const int b = (int)(u >> 24);
        binned[cur[b] + (p - loff[b])] = u;
    }
}

// ---------------------------------------------------------------------------
// Layer 1 node GEMM, standalone 256 threads: xw1b = bf16(x @ W1), logits.
// ---------------------------------------------------------------------------
__global__ __launch_bounds__(256) void k_node1(
    const float* __restrict__ x, const float* __restrict__ W1,
    const float* __restrict__ a_src, const float* __restrict__ a_dst,
    unsigned short* __restrict__ xw1b,
    float* __restrict__ al_s, float* __restrict__ al_d)
{
    __shared__ float sW[IN_CH * 132];        // 17952 B
    __shared__ float sx[32 * 35];            // 4480 B
    __shared__ float sas[128], sad[128];
    const int tid = threadIdx.x;
    for (int i = tid; i < IN_CH * 128; i += 256) {
        int k = i >> 7, c = i & 127;
        sW[k * 132 + c] = W1[i];
    }
    if (tid < 128) { sas[tid] = a_src[tid]; sad[tid] = a_dst[tid]; }
    const int n0 = blockIdx.x * 32;
    for (int i = tid; i < 32 * IN_CH; i += 256) {
        int n = i / IN_CH;
        sx[n * 35 + (i - n * IN_CH)] = (n0 + n < N_NODES) ? x[n0 * IN_CH + i] : 0.f;
    }
    __syncthreads();

    const int tc = tid & 31, tn = tid >> 5;
    float acc[4][4] = {{0.f}};
    for (int k = 0; k < IN_CH; ++k) {
        const float4 wv = *reinterpret_cast<const float4*>(&sW[k * 132 + 4 * tc]);
        #pragma unroll
        for (int j = 0; j < 4; ++j) {
            const float hj = sx[(4 * tn + j) * 35 + k];
            acc[j][0] += hj * wv.x; acc[j][1] += hj * wv.y;
            acc[j][2] += hj * wv.z; acc[j][3] += hj * wv.w;
        }
    }
    #pragma unroll
    for (int j = 0; j < 4; ++j) {
        const int node = n0 + 4 * tn + j;
        float ps = 0.f, pd = 0.f;
        #pragma unroll
        for (int c = 0; c < 4; ++c) {
            ps += acc[j][c] * sas[4 * tc + c];
            pd += acc[j][c] * sad[4 * tc + c];
        }
        #pragma unroll
        for (int off = 1; off < 16; off <<= 1) {
            ps += __shfl_xor(ps, off);
            pd += __shfl_xor(pd, off);
        }
        if (node < N_NODES) {
            if ((tc & 15) == 0) {
                int h = tc >> 4;
                al_s[node * 2 + h] = ps;
                al_d[node * 2 + h] = pd;
            }
            ushort4 u;
            u.x = f2bf(acc[j][0]); u.y = f2bf(acc[j][1]);
            u.z = f2bf(acc[j][2]); u.w = f2bf(acc[j][3]);
            *reinterpret_cast<ushort4*>(&xw1b[node * 128 + 4 * tc]) = u;
        }
    }
}

// ---------------------------------------------------------------------------
// Per-bucket fine sort, ATOMIC-FREE (same ballot-rank scheme as k_bin):
// 196 blocks x 1024 threads -> sorted_src + rowspan.
// ---------------------------------------------------------------------------
__global__ __launch_bounds__(1024) void k_fine(
    const int* __restrict__ gcur, const unsigned int* __restrict__ binned,
    int2* __restrict__ rowspan, int* __restrict__ sorted_src)
{
    __shared__ unsigned int sbin[CAP];     // 40 KB
    __shared__ unsigned int ssrt[CAP];     // 40 KB
    __shared__ int pcnt[16][256];          // 16 KB
    __shared__ int wsum[4];
    const int tid = threadIdx.x;
    const int wave = tid >> 6, lane = tid & 63;
    const unsigned long long below = (1ull << lane) - 1ull;
    const int b = blockIdx.x;
    const int bbase = b * CAP;
    const int cntb = gcur[b];
    const int nch = (cntb + 63) >> 6;

    for (int i = tid; i < 16 * 256; i += 1024) ((int*)pcnt)[i] = 0;
    __syncthreads();

    // P1: stage + per-wave ballot histogram over node-within-bucket key
    for (int c = wave; c < nch; c += 16) {
        const int idx = c * 64 + lane;
        const bool valid = idx < cntb;
        unsigned int u = 0;
        if (valid) { u = binned[bbase + idx]; sbin[idx] = u; }
        const int key = (int)((u >> 16) & 255u);
        const unsigned long long m = grp8(key, valid);
        if (valid && (m & below) == 0ull)
            pcnt[wave][key] += (int)__popcll(m);
    }
    __syncthreads();

    // P2: wave-prefix + block scan -> rowspan + wave cursors
    int run = 0;
    if (tid < 256) {
        #pragma unroll 1
        for (int w = 0; w < 16; ++w) {
            const int t = pcnt[w][tid];
            pcnt[w][tid] = run;
            run += t;
        }
    }
    const int excl = scan256_1024(run, wsum);
    if (tid < 256) {
        const int node = b * 256 + tid;
        if (node < N_NODES)
            rowspan[node] = make_int2(bbase + excl, bbase + excl + run);
        #pragma unroll 1
        for (int w = 0; w < 16; ++w) pcnt[w][tid] += excl;
    }
    __syncthreads();

    // P3: rank-based scatter into node-sorted ssrt (no atomics)
    for (int c = wave; c < nch; c += 16) {
        const int idx = c * 64 + lane;
        const bool valid = idx < cntb;
        const unsigned int u = valid ? sbin[idx] : 0u;
        const int key = (int)((u >> 16) & 255u);
        const unsigned long long m = grp8(key, valid);
        const int rank = (int)__popcll(m & below);
        const int leader = valid ? (__ffsll((long long)m) - 1) : 0;
        int basep = 0;
        if (valid && rank == 0) basep = pcnt[wave][key];
        basep = __shfl(basep, leader);
        if (valid) {
            ssrt[basep + rank] = u;
            if (rank == 0) pcnt[wave][key] = basep + (int)__popcll(m);
        }
    }
    __syncthreads();

    // P4: linear write-out of src ids
    for (int p = tid; p < cntb; p += 1024) {
        sorted_src[bbase + p] = (int)(ssrt[p] & 0xffffu);
    }
}

// ---------------------------------------------------------------------------
// Layer 1 gather: one wave per node; lane owns cols 2l,2l+1 (one uint/row).
// Per-head (offset,weight) pair-packed LDS arrays -> one ds_read_b128 per
// edge pair, no per-edge selects. fv2 accumulators (packed f32 fma).
// ---------------------------------------------------------------------------
__global__ __launch_bounds__(256) void k_gather1(
    const int2* __restrict__ rowspan, const int* __restrict__ sorted_src,
    const unsigned int* __restrict__ xw1u,    // 64 uints per row
    const float* __restrict__ al_s, const float* __restrict__ al_d,
    const float* __restrict__ b1, float* __restrict__ hbuf)
{
    __shared__ float4 AB[2][4][32];           // [head][wave][pair]=(offA,wA,offB,wB)
    const int wave = threadIdx.x >> 6;
    const int lane = threadIdx.x & 63;
    const int node = (blockIdx.x * 256 + threadIdx.x) >> 6;
    if (node >= N_NODES) return;
    const int2 span = rowspan[node];
    const int head = lane >> 5;

    const float2 ald  = *reinterpret_cast<const float2*>(&al_d[node * 2]);
    const float2 als0 = *reinterpret_cast<const float2*>(&al_s[node * 2]);
    const float w0h0 = lrelu_exp(als0.x + ald.x);
    const float w0h1 = lrelu_exp(als0.y + ald.y);
    const float wself = head ? w0h1 : w0h0;

    const unsigned int su = xw1u[node * 64 + lane];
    fv2 accX = { wself * bflo(su), wself * bfhi(su) };
    fv2 accY = { 0.f, 0.f };
    float dv0 = 0.f, dv1 = 0.f;
    const float4* ABh = AB[head][wave];

    for (int base = span.x; base < span.y; base += 64) {
        const int rem = span.y - base;
        const int m = rem < 64 ? rem : 64;
        const int mp = (m + 1) & ~1;
        if (lane < m) {
            const int s = sorted_src[base + lane];
            const float2 als = *reinterpret_cast<const float2*>(&al_s[s * 2]);
            const float w0 = lrelu_exp(als.x + ald.x);
            const float w1 = lrelu_exp(als.y + ald.y);
            dv0 += w0; dv1 += w1;
            const float offf = __int_as_float(s << 6);
            ((float2*)&AB[0][wave][lane >> 1])[lane & 1] = make_float2(offf, w0);
            ((float2*)&AB[1][wave][lane >> 1])[lane & 1] = make_float2(offf, w1);
        } else if (lane < mp) {
            const float offf = __int_as_float(node << 6);
            ((float2*)&AB[0][wave][lane >> 1])[lane & 1] = make_float2(offf, 0.f);
            ((float2*)&AB[1][wave][lane >> 1])[lane & 1] = make_float2(offf, 0.f);
        }
        const int P = mp >> 1;
        int p = 0;
        for (; p + 4 <= P; p += 4) {
            const float4 q0 = ABh[p + 0];
            const float4 q1 = ABh[p + 1];
            const float4 q2 = ABh[p + 2];
            const float4 q3 = ABh[p + 3];
            const unsigned int a0 = xw1u[__float_as_int(q0.x) + lane];
            const unsigned int b0 = xw1u[__float_as_int(q0.z) + lane];
            const unsigned int a1 = xw1u[__float_as_int(q1.x) + lane];
            const unsigned int b1v = xw1u[__float_as_int(q1.z) + lane];
            const unsigned int a2 = xw1u[__float_as_int(q2.x) + lane];
            const unsigned int b2 = xw1u[__float_as_int(q2.z) + lane];
            const unsigned int a3 = xw1u[__float_as_int(q3.x) + lane];
            const unsigned int b3 = xw1u[__float_as_int(q3.z) + lane];
            fv2 f;
            f.x = bflo(a0); f.y = bfhi(a0); accX += f * q0.y;
            f.x = bflo(b0); f.y = bfhi(b0); accY += f * q0.w;
            f.x = bflo(a1); f.y = bfhi(a1); accX += f * q1.y;
            f.x = bflo(b1v); f.y = bfhi(b1v); accY += f * q1.w;
            f.x = bflo(a2); f.y = bfhi(a2); accX += f * q2.y;
            f.x = bflo(b2); f.y = bfhi(b2); accY += f * q2.w;
            f.x = bflo(a3); f.y = bfhi(a3); accX += f * q3.y;
            f.x = bflo(b3); f.y = bfhi(b3); accY += f * q3.w;
        }
        for (; p < P; ++p) {
            const float4 q = ABh[p];
            const unsigned int a = xw1u[__float_as_int(q.x) + lane];
            const unsigned int b = xw1u[__float_as_int(q.z) + lane];
            fv2 f;
            f.x = bflo(a); f.y = bfhi(a); accX += f * q.y;
            f.x = bflo(b); f.y = bfhi(b); accY += f * q.w;
        }
    }
    accX += accY;
    #pragma unroll
    for (int off = 32; off; off >>= 1) {
        dv0 += __shfl_xor(dv0, off);
        dv1 += __shfl_xor(dv1, off);
    }
    const float den = head ? (dv1 + w0h1) : (dv0 + w0h0);
    const float2 bv = *reinterpret_cast<const float2*>(&b1[2 * lane]);
    float o0 = accX.x / den + bv.x;
    float o1 = accX.y / den + bv.y;
    o0 = o0 > 0.f ? o0 : 0.f;
    o1 = o1 > 0.f ? o1 : 0.f;
    *reinterpret_cast<float2*>(&hbuf[node * 128 + 2 * lane]) = make_float2(o0, o1);
}

// ---------------------------------------------------------------------------
// Layer 2 node pre-pass (register-tiled): xw2b = bf16(h @ W2) [N,64].
// ---------------------------------------------------------------------------
__global__ __launch_bounds__(256) void k_node2(
    const float* __restrict__ hbuf, const float* __restrict__ W2,
    const float* __restrict__ a_src, const float* __restrict__ a_dst,
    unsigned short* __restrict__ xw2b, float* __restrict__ al_s, float* __restrict__ al_d)
{
    __shared__ float sW[128 * 64];
    __shared__ float sh[64 * 129];
    __shared__ float sas[64], sad[64];
    const int tid = threadIdx.x;
    for (int i = tid; i < 128 * 64; i += 256) sW[i] = W2[i];
    if (tid < 64) { sas[tid] = a_src[tid]; sad[tid] = a_dst[tid]; }
    const int n0 = blockIdx.x * 64;
    for (int i = tid; i < 64 * 128; i += 256) {
        int n = i >> 7, c = i & 127;
        sh[n * 129 + c] = (n0 + n < N_NODES) ? hbuf[(long)(n0 + n) * 128 + c] : 0.f;
    }
    __syncthreads();

    const int tc = tid & 15, tn = tid >> 4;
    float acc[4][4] = {{0.f}};
    for (int k = 0; k < 128; ++k) {
        const float4 wv = *reinterpret_cast<const float4*>(&sW[k * 64 + 4 * tc]);
        #pragma unroll
        for (int j = 0; j < 4; ++j) {
            const float hj = sh[(4 * tn + j) * 129 + k];
            acc[j][0] += hj * wv.x; acc[j][1] += hj * wv.y;
            acc[j][2] += hj * wv.z; acc[j][3] += hj * wv.w;
        }
    }
    #pragma unroll
    for (int j = 0; j < 4; ++j) {
        const int node = n0 + 4 * tn + j;
        float ps = 0.f, pd = 0.f;
        #pragma unroll
        for (int c = 0; c < 4; ++c) {
            ps += acc[j][c] * sas[4 * tc + c];
            pd += acc[j][c] * sad[4 * tc + c];
        }
        #pragma unroll
        for (int off = 1; off < 16; off <<= 1) {
            ps += __shfl_xor(ps, off);
            pd += __shfl_xor(pd, off);
        }
        if (node < N_NODES) {
            if (tc == 0) { al_s[node] = ps; al_d[node] = pd; }
            ushort4 u;
            u.x = f2bf(acc[j][0]); u.y = f2bf(acc[j][1]);
            u.z = f2bf(acc[j][2]); u.w = f2bf(acc[j][3]);
            *reinterpret_cast<ushort4*>(&xw2b[node * 64 + 4 * tc]) = u;
        }
    }
}

// ---------------------------------------------------------------------------
// Layer 2 gather: half-wave per edge pair (4 edges/step), pair-packed
// (offset,weight) LDS, fv2 accumulators. out = acc/den + b2.
// ---------------------------------------------------------------------------
__global__ __launch_bounds__(256) void k_gather2(
    const int2* __restrict__ rowspan, const int* __restrict__ sorted_src,
    const unsigned int* __restrict__ xw2u,    // 32 uints per row
    const float* __restrict__ al_s, const float* __restrict__ al_d,
    const float* __restrict__ b2, float* __restrict__ out)
{
    __shared__ float4 AB[4][32];              // [wave][pair]=(offA,wA,offB,wB)
    const int wave = threadIdx.x >> 6;
    const int lane = threadIdx.x & 63;
    const int node = (blockIdx.x * 256 + threadIdx.x) >> 6;
    if (node >= N_NODES) return;
    const int2 span = rowspan[node];
    const int li = lane & 31, hsel = lane >> 5;

    const float ald = al_d[node];
    const float w0s = lrelu_exp(al_s[node] + ald);
    const unsigned int su = xw2u[node * 32 + li];
    const float wself = hsel ? 0.f : w0s;
    fv2 acc = { wself * bflo(su), wself * bfhi(su) };
    float dv = 0.f;
    const float4* ABw = AB[wave];

    for (int base = span.x; base < span.y; base += 64) {
        const int rem = span.y - base;
        const int m = rem < 64 ? rem : 64;
        const int mp = (m + 3) & ~3;
        if (lane < m) {
            const int s = sorted_src[base + lane];
            const float w = lrelu_exp(al_s[s] + ald);
            dv += w;
            ((float2*)&AB[wave][lane >> 1])[lane & 1] =
                make_float2(__int_as_float(s << 5), w);
        } else if (lane < mp) {
            ((float2*)&AB[wave][lane >> 1])[lane & 1] =
                make_float2(__int_as_float(node << 5), 0.f);
        }
        const int P = mp >> 1;                // even
        int p = hsel;
        for (; p + 2 < P; p += 4) {
            const float4 qA = ABw[p];
            const float4 qB = ABw[p + 2];
            const unsigned int aA = xw2u[__float_as_int(qA.x) + li];
            const unsigned int bA = xw2u[__float_as_int(qA.z) + li];
            const unsigned int aB = xw2u[__float_as_int(qB.x) + li];
            const unsigned int bB = xw2u[__float_as_int(qB.z) + li];
            fv2 f;
            f.x = bflo(aA); f.y = bfhi(aA); acc += f * qA.y;
            f.x = bflo(bA); f.y = bfhi(bA); acc += f * qA.w;
            f.x = bflo(aB); f.y = bfhi(aB); acc += f * qB.y;
            f.x = bflo(bB); f.y = bfhi(bB); acc += f * qB.w;
        }
        for (; p < P; p += 2) {
            const float4 q = ABw[p];
            const unsigned int a = xw2u[__float_as_int(q.x) + li];
            const unsigned int b = xw2u[__float_as_int(q.z) + li];
            fv2 f;
            f.x = bflo(a); f.y = bfhi(a); acc += f * q.y;
            f.x = bflo(b); f.y = bfhi(b); acc += f * q.w;
        }
    }
    acc.x += __shfl_xor(acc.x, 32);
    acc.y += __shfl_xor(acc.y, 32);
    #pragma unroll
    for (int off = 32; off; off >>= 1) dv += __shfl_xor(dv, off);
    if (lane < 32) {
        const float den = dv + w0s;
        const float2 bv = *reinterpret_cast<const float2*>(&b2[2 * li]);
        *reinterpret_cast<float2*>(&out[node * 64 + 2 * li]) =
            make_float2(acc.x / den + bv.x, acc.y / den + bv.y);
    }
}

extern "C" void kernel_launch(void* const* d_in, const int* in_sizes, int n_in,
                              void* d_out, int out_size, void* d_ws, size_t ws_size,
                              hipStream_t stream)
{
    const float* x   = (const float*)d_in[0];
    const int*   ei  = (const int*)d_in[1];
    const float* W1  = (const float*)d_in[2];
    const float* as1 = (const float*)d_in[3];
    const float* ad1 = (const float*)d_in[4];
    const float* b1  = (const float*)d_in[5];
    const float* W2  = (const float*)d_in[6];
    const float* as2 = (const float*)d_in[7];
    const float* ad2 = (const float*)d_in[8];
    const float* b2  = (const float*)d_in[9];
    float* out = (float*)d_out;

    const int* srcA = ei;
    const int* dstA = ei + E_EDGES;

    // Workspace layout (bytes). Total 54,251,648 B.
    char* ws = (char*)d_ws;
    int2*  rowspan    = (int2*)(ws);                         // 400 KB (pad 409,600)
    int*   sorted_src = (int*)(ws + 409600);                 // 7.84 MB
    int*   gcur       = (int*)(ws + 8249600);                // NB ints (pad 2 KB)
    float* al_s1      = (float*)(ws + 8251648);              // 400 KB
    float* al_d1      = (float*)(ws + 8651648);              // 400 KB
    float* al_s2      = (float*)(ws + 9051648);              // 200 KB
    float* al_d2      = (float*)(ws + 9251648);              // 200 KB
    unsigned short* xw1b = (unsigned short*)(ws + 9451648);  // 12.8 MB bf16
    float* hbuf       = (float*)(ws + 22251648);             // 25.6 MB fp32
    unsigned int* binned = (unsigned int*)hbuf;              // alias: dead before gather1
    unsigned short* xw2b = (unsigned short*)(ws + 47851648); // 6.4 MB bf16

    hipMemsetAsync(gcur, 0, NB * sizeof(int), stream);
    hipLaunchKernelGGL(k_bin, dim3(NB), dim3(1024), 0, stream,
                       srcA, dstA, gcur, binned);
    hipLaunchKernelGGL(k_node1, dim3((N_NODES + 31) / 32), dim3(256), 0, stream,
                       x, W1, as1, ad1, xw1b, al_s1, al_d1);
    hipLaunchKernelGGL(k_fine, dim3(NB), dim3(1024), 0, stream,
                       gcur, binned, rowspan, sorted_src);
    hipLaunchKernelGGL(k_gather1, dim3((N_NODES + 3) / 4), dim3(256), 0, stream,
                       rowspan, sorted_src, (const unsigned int*)xw1b,
                       al_s1, al_d1, b1, hbuf);
    hipLaunchKernelGGL(k_node2, dim3((N_NODES + 63) / 64), dim3(256), 0, stream,
                       hbuf, W2, as2, ad2, xw2b, al_s2, al_d2);
    hipLaunchKernelGGL(k_gather2, dim3((N_NODES + 3) / 4), dim3(256), 0, stream,
                       rowspan, sorted_src, (const unsigned int*)xw2b,
                       al_s2, al_d2, b2, out);
}

// Round 9
// 258.761 us; speedup vs baseline: 8.8591x; 1.0681x over previous
//
#include <hip/hip_runtime.h>
#include <math.h>

#define N_NODES 50000
#define E_EDGES 1600000
#define IN_CH   34
#define NEG     0.2f
#define NB      196          // coarse buckets: dst>>8
#define CAP     10000        // bucket capacity (E[8163], sigma~90)
#define EPB     4096         // edges per bin block
#define NBB     391          // ceil(E_EDGES / EPB)

typedef __attribute__((ext_vector_type(2))) float fv2;

static __device__ __forceinline__ unsigned short f2bf(float f) {
    unsigned int u = __float_as_uint(f);
    u += 0x7fffu + ((u >> 16) & 1u);
    return (unsigned short)(u >> 16);
}
static __device__ __forceinline__ float bflo(unsigned int u) {
    return __uint_as_float(u << 16);
}
static __device__ __forceinline__ float bfhi(unsigned int u) {
    return __uint_as_float(u & 0xffff0000u);
}
static __device__ __forceinline__ float lrelu_exp(float e) {
    return expf(e > 0.f ? e : NEG * e);
}

// 256-thread block exclusive scan. wsum = int[4] LDS scratch.
static __device__ __forceinline__ int scan256_excl(int v, int* wsum) {
    const int lane = threadIdx.x & 63, wv = threadIdx.x >> 6;
    int x = v;
    #pragma unroll
    for (int off = 1; off < 64; off <<= 1) {
        int y = __shfl_up(x, off);
        if (lane >= off) x += y;
    }
    if (lane == 63) wsum[wv] = x;
    __syncthreads();
    if (threadIdx.x < 4) {
        int s = wsum[threadIdx.x];
        #pragma unroll
        for (int off = 1; off < 4; off <<= 1) {
            int y = __shfl_up(s, off);
            if ((int)threadIdx.x >= off) s += y;
        }
        wsum[threadIdx.x] = s;
    }
    __syncthreads();
    const int woff = wv ? wsum[wv - 1] : 0;
    return woff + x - v;
}

// Exclusive scan over 256 values in a 1024-thread block (all threads call).
static __device__ __forceinline__ int scan256_1024(int v, int* wsum) {
    const int lane = threadIdx.x & 63, wv = threadIdx.x >> 6;
    int x = v;
    #pragma unroll
    for (int off = 1; off < 64; off <<= 1) {
        int y = __shfl_up(x, off);
        if (lane >= off) x += y;
    }
    if (wv < 4 && lane == 63) wsum[wv] = x;
    __syncthreads();
    if (threadIdx.x < 4) {
        int s = wsum[threadIdx.x];
        #pragma unroll
        for (int off = 1; off < 4; off <<= 1) {
            int y = __shfl_up(s, off);
            if ((int)threadIdx.x >= off) s += y;
        }
        wsum[threadIdx.x] = s;
    }
    __syncthreads();
    const int woff = (wv >= 1 && wv < 4) ? wsum[wv - 1] : 0;
    return woff + x - v;
}

// ---------------------------------------------------------------------------
// Fused: blocks [0,NBB) bin 4096 edges each into bucket-strided `binned`;
// blocks [NBB,..) run the layer-1 node GEMM. LDS union = 36.9 KB -> 4
// blocks/CU so the two roles genuinely interleave (r4's 70 KB capped at 2).
// gcur must be zeroed beforehand; 391 blocks -> gcur atomic depth ~2/bucket.
// ---------------------------------------------------------------------------
__global__ __launch_bounds__(256) void k_bin_node1(
    const int* __restrict__ srcA, const int* __restrict__ dstA,
    int* __restrict__ gcur, unsigned int* __restrict__ binned,
    const float* __restrict__ x, const float* __restrict__ W1,
    const float* __restrict__ a_src, const float* __restrict__ a_dst,
    unsigned short* __restrict__ xw1b,
    float* __restrict__ al_s, float* __restrict__ al_d)
{
    __shared__ __align__(16) char sm[36880];
    const int tid = threadIdx.x;

    if (blockIdx.x < NBB) {
        // ---- binning role ----
        unsigned int* raw  = (unsigned int*)sm;            // 16384 B
        unsigned int* ebuf = (unsigned int*)(sm + 16384);  // 16384 B
        int* cnt  = (int*)(sm + 32768);
        int* loff = (int*)(sm + 33792);
        int* lcur = (int*)(sm + 34816);
        int* cur  = (int*)(sm + 35840);
        int* wsum = (int*)(sm + 36864);
        cnt[tid] = 0;
        __syncthreads();
        const int base = blockIdx.x * EPB;
        const int mE = min(EPB, E_EDGES - base);           // %4 == 0
        const int nq = mE >> 2;
        for (int q = tid; q < nq; q += 256) {
            const int4 d4 = ((const int4*)(dstA + base))[q];
            const int4 s4 = ((const int4*)(srcA + base))[q];
            raw[4 * q + 0] = ((unsigned)d4.x << 16) | (unsigned)s4.x;
            raw[4 * q + 1] = ((unsigned)d4.y << 16) | (unsigned)s4.y;
            raw[4 * q + 2] = ((unsigned)d4.z << 16) | (unsigned)s4.z;
            raw[4 * q + 3] = ((unsigned)d4.w << 16) | (unsigned)s4.w;
            atomicAdd(&cnt[d4.x >> 8], 1);
            atomicAdd(&cnt[d4.y >> 8], 1);
            atomicAdd(&cnt[d4.z >> 8], 1);
            atomicAdd(&cnt[d4.w >> 8], 1);
        }
        __syncthreads();
        const int v = cnt[tid];
        const int excl = scan256_excl(v, wsum);
        loff[tid] = excl;
        lcur[tid] = excl;
        cur[tid] = (tid < NB && v > 0) ? (tid * CAP + atomicAdd(&gcur[tid], v)) : 0;
        __syncthreads();
        for (int p = tid; p < mE; p += 256) {
            const unsigned int u = raw[p];
            const int q = atomicAdd(&lcur[u >> 24], 1);
            ebuf[q] = u;
        }
        __syncthreads();
        for (int p = tid; p < mE; p += 256) {
            const unsigned int u = ebuf[p];
            const int b = (int)(u >> 24);
            binned[cur[b] + (p - loff[b])] = u;
        }
    } else {
        // ---- node1 role: xw1b = bf16(x @ W1), logits al_s/al_d ----
        float* sW  = (float*)sm;                 // 34*132*4 = 17952 B
        float* sx  = (float*)(sm + 17952);       // 32*35*4  = 4480 B
        float* sas = (float*)(sm + 22432);       // 512 B
        float* sad = (float*)(sm + 22944);       // 512 B
        for (int i = tid; i < IN_CH * 128; i += 256) {
            int k = i >> 7, c = i & 127;
            sW[k * 132 + c] = W1[i];
        }
        if (tid < 128) { sas[tid] = a_src[tid]; sad[tid] = a_dst[tid]; }
        const int n0 = (blockIdx.x - NBB) * 32;
        for (int i = tid; i < 32 * IN_CH; i += 256) {
            int n = i / IN_CH;
            sx[n * 35 + (i - n * IN_CH)] = (n0 + n < N_NODES) ? x[n0 * IN_CH + i] : 0.f;
        }
        __syncthreads();

        const int tc = tid & 31, tn = tid >> 5;
        float acc[4][4] = {{0.f}};
        for (int k = 0; k < IN_CH; ++k) {
            const float4 wv = *reinterpret_cast<const float4*>(&sW[k * 132 + 4 * tc]);
            #pragma unroll
            for (int j = 0; j < 4; ++j) {
                const float hj = sx[(4 * tn + j) * 35 + k];
                acc[j][0] += hj * wv.x; acc[j][1] += hj * wv.y;
                acc[j][2] += hj * wv.z; acc[j][3] += hj * wv.w;
            }
        }
        #pragma unroll
        for (int j = 0; j < 4; ++j) {
            const int node = n0 + 4 * tn + j;
            float ps = 0.f, pd = 0.f;
            #pragma unroll
            for (int c = 0; c < 4; ++c) {
                ps += acc[j][c] * sas[4 * tc + c];
                pd += acc[j][c] * sad[4 * tc + c];
            }
            #pragma unroll
            for (int off = 1; off < 16; off <<= 1) {
                ps += __shfl_xor(ps, off);
                pd += __shfl_xor(pd, off);
            }
            if (node < N_NODES) {
                if ((tc & 15) == 0) {
                    int h = tc >> 4;
                    al_s[node * 2 + h] = ps;
                    al_d[node * 2 + h] = pd;
                }
                ushort4 u;
                u.x = f2bf(acc[j][0]); u.y = f2bf(acc[j][1]);
                u.z = f2bf(acc[j][2]); u.w = f2bf(acc[j][3]);
                *reinterpret_cast<ushort4*>(&xw1b[node * 128 + 4 * tc]) = u;
            }
        }
    }
}

// ---------------------------------------------------------------------------
// Per-bucket fine sort (LDS-staged) -> sorted_src + rowspan.
// 1024 threads (16 waves, 4/SIMD) hide the LDS-atomic latency chains.
// ---------------------------------------------------------------------------
__global__ __launch_bounds__(1024) void k_fine(
    const int* __restrict__ gcur, const unsigned int* __restrict__ binned,
    int2* __restrict__ rowspan, int* __restrict__ sorted_src)
{
    __shared__ unsigned int sbin[CAP];    // 40 KB
    __shared__ int cnt[256], lcur[256];
    __shared__ int wsum[4];
    const int tid = threadIdx.x;
    const int b = blockIdx.x;
    const int bbase = b * CAP;
    const int cntb = gcur[b];
    if (tid < 256) cnt[tid] = 0;
    __syncthreads();
    for (int p = tid; p < cntb; p += 1024) {
        const unsigned int u = binned[bbase + p];
        sbin[p] = u;
        atomicAdd(&cnt[(u >> 16) & 255], 1);
    }
    __syncthreads();
    const int v = (tid < 256) ? cnt[tid] : 0;
    const int excl = scan256_1024(v, wsum);
    if (tid < 256) {
        lcur[tid] = excl;
        const int node = b * 256 + tid;
        if (node < N_NODES) rowspan[node] = make_int2(bbase + excl, bbase + excl + v);
    }
    __syncthreads();
    for (int p = tid; p < cntb; p += 1024) {
        const unsigned int u = sbin[p];
        const int q = atomicAdd(&lcur[(u >> 16) & 255], 1);
        sorted_src[bbase + q] = (int)(u & 0xffffu);
    }
}

// ---------------------------------------------------------------------------
// Layer 1 gather: one wave per node; lane owns cols 2l,2l+1 (one uint/row).
// Per-head (offset,weight) pair-packed LDS arrays -> one ds_read_b128 per
// edge pair, no per-edge selects. fv2 accumulators (packed f32 fma).
// ---------------------------------------------------------------------------
__global__ __launch_bounds__(256) void k_gather1(
    const int2* __restrict__ rowspan, const int* __restrict__ sorted_src,
    const unsigned int* __restrict__ xw1u,    // 64 uints per row
    const float* __restrict__ al_s, const float* __restrict__ al_d,
    const float* __restrict__ b1, float* __restrict__ hbuf)
{
    __shared__ float4 AB[2][4][32];           // [head][wave][pair]=(offA,wA,offB,wB)
    const int wave = threadIdx.x >> 6;
    const int lane = threadIdx.x & 63;
    const int node = (blockIdx.x * 256 + threadIdx.x) >> 6;
    if (node >= N_NODES) return;
    const int2 span = rowspan[node];
    const int head = lane >> 5;

    const float2 ald  = *reinterpret_cast<const float2*>(&al_d[node * 2]);
    const float2 als0 = *reinterpret_cast<const float2*>(&al_s[node * 2]);
    const float w0h0 = lrelu_exp(als0.x + ald.x);
    const float w0h1 = lrelu_exp(als0.y + ald.y);
    const float wself = head ? w0h1 : w0h0;

    const unsigned int su = xw1u[node * 64 + lane];
    fv2 accX = { wself * bflo(su), wself * bfhi(su) };
    fv2 accY = { 0.f, 0.f };
    float dv0 = 0.f, dv1 = 0.f;
    const float4* ABh = AB[head][wave];

    for (int base = span.x; base < span.y; base += 64) {
        const int rem = span.y - base;
        const int m = rem < 64 ? rem : 64;
        const int mp = (m + 1) & ~1;
        if (lane < m) {
            const int s = sorted_src[base + lane];
            const float2 als = *reinterpret_cast<const float2*>(&al_s[s * 2]);
            const float w0 = lrelu_exp(als.x + ald.x);
            const float w1 = lrelu_exp(als.y + ald.y);
            dv0 += w0; dv1 += w1;
            const float offf = __int_as_float(s << 6);
            ((float2*)&AB[0][wave][lane >> 1])[lane & 1] = make_float2(offf, w0);
            ((float2*)&AB[1][wave][lane >> 1])[lane & 1] = make_float2(offf, w1);
        } else if (lane < mp) {
            const float offf = __int_as_float(node << 6);
            ((float2*)&AB[0][wave][lane >> 1])[lane & 1] = make_float2(offf, 0.f);
            ((float2*)&AB[1][wave][lane >> 1])[lane & 1] = make_float2(offf, 0.f);
        }
        const int P = mp >> 1;
        int p = 0;
        for (; p + 4 <= P; p += 4) {
            const float4 q0 = ABh[p + 0];
            const float4 q1 = ABh[p + 1];
            const float4 q2 = ABh[p + 2];
            const float4 q3 = ABh[p + 3];
            const unsigned int a0 = xw1u[__float_as_int(q0.x) + lane];
            const unsigned int b0 = xw1u[__float_as_int(q0.z) + lane];
            const unsigned int a1 = xw1u[__float_as_int(q1.x) + lane];
            const unsigned int b1v = xw1u[__float_as_int(q1.z) + lane];
            const unsigned int a2 = xw1u[__float_as_int(q2.x) + lane];
            const unsigned int b2 = xw1u[__float_as_int(q2.z) + lane];
            const unsigned int a3 = xw1u[__float_as_int(q3.x) + lane];
            const unsigned int b3 = xw1u[__float_as_int(q3.z) + lane];
            fv2 f;
            f.x = bflo(a0); f.y = bfhi(a0); accX += f * q0.y;
            f.x = bflo(b0); f.y = bfhi(b0); accY += f * q0.w;
            f.x = bflo(a1); f.y = bfhi(a1); accX += f * q1.y;
            f.x = bflo(b1v); f.y = bfhi(b1v); accY += f * q1.w;
            f.x = bflo(a2); f.y = bfhi(a2); accX += f * q2.y;
            f.x = bflo(b2); f.y = bfhi(b2); accY += f * q2.w;
            f.x = bflo(a3); f.y = bfhi(a3); accX += f * q3.y;
            f.x = bflo(b3); f.y = bfhi(b3); accY += f * q3.w;
        }
        for (; p < P; ++p) {
            const float4 q = ABh[p];
            const unsigned int a = xw1u[__float_as_int(q.x) + lane];
            const unsigned int b = xw1u[__float_as_int(q.z) + lane];
            fv2 f;
            f.x = bflo(a); f.y = bfhi(a); accX += f * q.y;
            f.x = bflo(b); f.y = bfhi(b); accY += f * q.w;
        }
    }
    accX += accY;
    #pragma unroll
    for (int off = 32; off; off >>= 1) {
        dv0 += __shfl_xor(dv0, off);
        dv1 += __shfl_xor(dv1, off);
    }
    const float den = head ? (dv1 + w0h1) : (dv0 + w0h0);
    const float2 bv = *reinterpret_cast<const float2*>(&b1[2 * lane]);
    float o0 = accX.x / den + bv.x;
    float o1 = accX.y / den + bv.y;
    o0 = o0 > 0.f ? o0 : 0.f;
    o1 = o1 > 0.f ? o1 : 0.f;
    *reinterpret_cast<float2*>(&hbuf[node * 128 + 2 * lane]) = make_float2(o0, o1);
}

// ---------------------------------------------------------------------------
// Layer 2 node pre-pass (register-tiled): xw2b = bf16(h @ W2) [N,64].
// ---------------------------------------------------------------------------
__global__ __launch_bounds__(256) void k_node2(
    const float* __restrict__ hbuf, const float* __restrict__ W2,
    const float* __restrict__ a_src, const float* __restrict__ a_dst,
    unsigned short* __restrict__ xw2b, float* __restrict__ al_s, float* __restrict__ al_d)
{
    __shared__ float sW[128 * 64];
    __shared__ float sh[64 * 129];
    __shared__ float sas[64], sad[64];
    const int tid = threadIdx.x;
    for (int i = tid; i < 128 * 64; i += 256) sW[i] = W2[i];
    if (tid < 64) { sas[tid] = a_src[tid]; sad[tid] = a_dst[tid]; }
    const int n0 = blockIdx.x * 64;
    for (int i = tid; i < 64 * 128; i += 256) {
        int n = i >> 7, c = i & 127;
        sh[n * 129 + c] = (n0 + n < N_NODES) ? hbuf[(long)(n0 + n) * 128 + c] : 0.f;
    }
    __syncthreads();

    const int tc = tid & 15, tn = tid >> 4;
    float acc[4][4] = {{0.f}};
    for (int k = 0; k < 128; ++k) {
        const float4 wv = *reinterpret_cast<const float4*>(&sW[k * 64 + 4 * tc]);
        #pragma unroll
        for (int j = 0; j < 4; ++j) {
            const float hj = sh[(4 * tn + j) * 129 + k];
            acc[j][0] += hj * wv.x; acc[j][1] += hj * wv.y;
            acc[j][2] += hj * wv.z; acc[j][3] += hj * wv.w;
        }
    }
    #pragma unroll
    for (int j = 0; j < 4; ++j) {
        const int node = n0 + 4 * tn + j;
        float ps = 0.f, pd = 0.f;
        #pragma unroll
        for (int c = 0; c < 4; ++c) {
            ps += acc[j][c] * sas[4 * tc + c];
            pd += acc[j][c] * sad[4 * tc + c];
        }
        #pragma unroll
        for (int off = 1; off < 16; off <<= 1) {
            ps += __shfl_xor(ps, off);
            pd += __shfl_xor(pd, off);
        }
        if (node < N_NODES) {
            if (tc == 0) { al_s[node] = ps; al_d[node] = pd; }
            ushort4 u;
            u.x = f2bf(acc[j][0]); u.y = f2bf(acc[j][1]);
            u.z = f2bf(acc[j][2]); u.w = f2bf(acc[j][3]);
            *reinterpret_cast<ushort4*>(&xw2b[node * 64 + 4 * tc]) = u;
        }
    }
}

// ---------------------------------------------------------------------------
// Layer 2 gather: half-wave per edge pair (4 edges/step), pair-packed
// (offset,weight) LDS, fv2 accumulators. out = acc/den + b2.
// ---------------------------------------------------------------------------
__global__ __launch_bounds__(256) void k_gather2(
    const int2* __restrict__ rowspan, const int* __restrict__ sorted_src,
    const unsigned int* __restrict__ xw2u,    // 32 uints per row
    const float* __restrict__ al_s, const float* __restrict__ al_d,
    const float* __restrict__ b2, float* __restrict__ out)
{
    __shared__ float4 AB[4][32];              // [wave][pair]=(offA,wA,offB,wB)
    const int wave = threadIdx.x >> 6;
    const int lane = threadIdx.x & 63;
    const int node = (blockIdx.x * 256 + threadIdx.x) >> 6;
    if (node >= N_NODES) return;
    const int2 span = rowspan[node];
    const int li = lane & 31, hsel = lane >> 5;

    const float ald = al_d[node];
    const float w0s = lrelu_exp(al_s[node] + ald);
    const unsigned int su = xw2u[node * 32 + li];
    const float wself = hsel ? 0.f : w0s;
    fv2 acc = { wself * bflo(su), wself * bfhi(su) };
    float dv = 0.f;
    const float4* ABw = AB[wave];

    for (int base = span.x; base < span.y; base += 64) {
        const int rem = span.y - base;
        const int m = rem < 64 ? rem : 64;
        const int mp = (m + 3) & ~3;
        if (lane < m) {
            const int s = sorted_src[base + lane];
            const float w = lrelu_exp(al_s[s] + ald);
            dv += w;
            ((float2*)&AB[wave][lane >> 1])[lane & 1] =
                make_float2(__int_as_float(s << 5), w);
        } else if (lane < mp) {
            ((float2*)&AB[wave][lane >> 1])[lane & 1] =
                make_float2(__int_as_float(node << 5), 0.f);
        }
        const int P = mp >> 1;                // even
        int p = hsel;
        for (; p + 2 < P; p += 4) {
            const float4 qA = ABw[p];
            const float4 qB = ABw[p + 2];
            const unsigned int aA = xw2u[__float_as_int(qA.x) + li];
            const unsigned int bA = xw2u[__float_as_int(qA.z) + li];
            const unsigned int aB = xw2u[__float_as_int(qB.x) + li];
            const unsigned int bB = xw2u[__float_as_int(qB.z) + li];
            fv2 f;
            f.x = bflo(aA); f.y = bfhi(aA); acc += f * qA.y;
            f.x = bflo(bA); f.y = bfhi(bA); acc += f * qA.w;
            f.x = bflo(aB); f.y = bfhi(aB); acc += f * qB.y;
            f.x = bflo(bB); f.y = bfhi(bB); acc += f * qB.w;
        }
        for (; p < P; p += 2) {
            const float4 q = ABw[p];
            const unsigned int a = xw2u[__float_as_int(q.x) + li];
            const unsigned int b = xw2u[__float_as_int(q.z) + li];
            fv2 f;
            f.x = bflo(a); f.y = bfhi(a); acc += f * q.y;
            f.x = bflo(b); f.y = bfhi(b); acc += f * q.w;
        }
    }
    acc.x += __shfl_xor(acc.x, 32);
    acc.y += __shfl_xor(acc.y, 32);
    #pragma unroll
    for (int off = 32; off; off >>= 1) dv += __shfl_xor(dv, off);
    if (lane < 32) {
        const float den = dv + w0s;
        const float2 bv = *reinterpret_cast<const float2*>(&b2[2 * li]);
        *reinterpret_cast<float2*>(&out[node * 64 + 2 * li]) =
            make_float2(acc.x / den + bv.x, acc.y / den + bv.y);
    }
}

extern "C" void kernel_launch(void* const* d_in, const int* in_sizes, int n_in,
                              void* d_out, int out_size, void* d_ws, size_t ws_size,
                              hipStream_t stream)
{
    const float* x   = (const float*)d_in[0];
    const int*   ei  = (const int*)d_in[1];
    const float* W1  = (const float*)d_in[2];
    const float* as1 = (const float*)d_in[3];
    const float* ad1 = (const float*)d_in[4];
    const float* b1  = (const float*)d_in[5];
    const float* W2  = (const float*)d_in[6];
    const float* as2 = (const float*)d_in[7];
    const float* ad2 = (const float*)d_in[8];
    const float* b2  = (const float*)d_in[9];
    float* out = (float*)d_out;

    const int* srcA = ei;
    const int* dstA = ei + E_EDGES;

    // Workspace layout (bytes). Total 54,251,648 B.
    char* ws = (char*)d_ws;
    int2*  rowspan    = (int2*)(ws);                         // 400 KB (pad 409,600)
    int*   sorted_src = (int*)(ws + 409600);                 // 7.84 MB
    int*   gcur       = (int*)(ws + 8249600);                // NB ints (pad 2 KB)
    float* al_s1      = (float*)(ws + 8251648);              // 400 KB
    float* al_d1      = (float*)(ws + 8651648);              // 400 KB
    float* al_s2      = (float*)(ws + 9051648);              // 200 KB
    float* al_d2      = (float*)(ws + 9251648);              // 200 KB
    unsigned short* xw1b = (unsigned short*)(ws + 9451648);  // 12.8 MB bf16
    float* hbuf       = (float*)(ws + 22251648);             // 25.6 MB fp32
    unsigned int* binned = (unsigned int*)hbuf;              // alias: dead before gather1
    unsigned short* xw2b = (unsigned short*)(ws + 47851648); // 6.4 MB bf16

    hipMemsetAsync(gcur, 0, NB * sizeof(int), stream);
    hipLaunchKernelGGL(k_bin_node1, dim3(NBB + (N_NODES + 31) / 32), dim3(256), 0, stream,
                       srcA, dstA, gcur, binned,
                       x, W1, as1, ad1, xw1b, al_s1, al_d1);
    hipLaunchKernelGGL(k_fine, dim3(NB), dim3(1024), 0, stream,
                       gcur, binned, rowspan, sorted_src);
    hipLaunchKernelGGL(k_gather1, dim3((N_NODES + 3) / 4), dim3(256), 0, stream,
                       rowspan, sorted_src, (const unsigned int*)xw1b,
                       al_s1, al_d1, b1, hbuf);
    hipLaunchKernelGGL(k_node2, dim3((N_NODES + 63) / 64), dim3(256), 0, stream,
                       hbuf, W2, as2, ad2, xw2b, al_s2, al_d2);
    hipLaunchKernelGGL(k_gather2, dim3((N_NODES + 3) / 4), dim3(256), 0, stream,
                       rowspan, sorted_src, (const unsigned int*)xw2b,
                       al_s2, al_d2, b2, out);
}

// Round 10
// 249.306 us; speedup vs baseline: 9.1951x; 1.0379x over previous
//
#include <hip/hip_runtime.h>
#include <math.h>

#define N_NODES 50000
#define E_EDGES 1600000
#define IN_CH   34
#define NEG     0.2f
#define NB      196          // coarse buckets: dst>>8
#define CAP     10000        // bucket capacity (E[8163], sigma~90)
#define EPB     4096         // edges per bin block
#define NBB     391          // ceil(E_EDGES / EPB)

typedef __attribute__((ext_vector_type(2))) float fv2;

static __device__ __forceinline__ unsigned short f2bf(float f) {
    unsigned int u = __float_as_uint(f);
    u += 0x7fffu + ((u >> 16) & 1u);
    return (unsigned short)(u >> 16);
}
static __device__ __forceinline__ float bflo(unsigned int u) {
    return __uint_as_float(u << 16);
}
static __device__ __forceinline__ float bfhi(unsigned int u) {
    return __uint_as_float(u & 0xffff0000u);
}
static __device__ __forceinline__ float lrelu_exp(float e) {
    return expf(e > 0.f ? e : NEG * e);
}

// 256-thread block exclusive scan. wsum = int[4] LDS scratch.
static __device__ __forceinline__ int scan256_excl(int v, int* wsum) {
    const int lane = threadIdx.x & 63, wv = threadIdx.x >> 6;
    int x = v;
    #pragma unroll
    for (int off = 1; off < 64; off <<= 1) {
        int y = __shfl_up(x, off);
        if (lane >= off) x += y;
    }
    if (lane == 63) wsum[wv] = x;
    __syncthreads();
    if (threadIdx.x < 4) {
        int s = wsum[threadIdx.x];
        #pragma unroll
        for (int off = 1; off < 4; off <<= 1) {
            int y = __shfl_up(s, off);
            if ((int)threadIdx.x >= off) s += y;
        }
        wsum[threadIdx.x] = s;
    }
    __syncthreads();
    const int woff = wv ? wsum[wv - 1] : 0;
    return woff + x - v;
}

// Exclusive scan over 256 values in a 1024-thread block (all threads call).
static __device__ __forceinline__ int scan256_1024(int v, int* wsum) {
    const int lane = threadIdx.x & 63, wv = threadIdx.x >> 6;
    int x = v;
    #pragma unroll
    for (int off = 1; off < 64; off <<= 1) {
        int y = __shfl_up(x, off);
        if (lane >= off) x += y;
    }
    if (wv < 4 && lane == 63) wsum[wv] = x;
    __syncthreads();
    if (threadIdx.x < 4) {
        int s = wsum[threadIdx.x];
        #pragma unroll
        for (int off = 1; off < 4; off <<= 1) {
            int y = __shfl_up(s, off);
            if ((int)threadIdx.x >= off) s += y;
        }
        wsum[threadIdx.x] = s;
    }
    __syncthreads();
    const int woff = (wv >= 1 && wv < 4) ? wsum[wv - 1] : 0;
    return woff + x - v;
}

// ---------------------------------------------------------------------------
// Fused: blocks [0,NBB) bin 4096 edges each into bucket-strided `binned`;
// blocks [NBB,..) run the layer-1 node GEMM (float4 LDS reads on both
// operands: sx padded to stride 36 so 4-k chunks read b128).
// gcur must be zeroed beforehand.
// ---------------------------------------------------------------------------
__global__ __launch_bounds__(256) void k_bin_node1(
    const int* __restrict__ srcA, const int* __restrict__ dstA,
    int* __restrict__ gcur, unsigned int* __restrict__ binned,
    const float* __restrict__ x, const float* __restrict__ W1,
    const float* __restrict__ a_src, const float* __restrict__ a_dst,
    unsigned short* __restrict__ xw1b,
    float* __restrict__ al_s, float* __restrict__ al_d)
{
    __shared__ __align__(16) char sm[36880];
    const int tid = threadIdx.x;

    if (blockIdx.x < NBB) {
        // ---- binning role ----
        unsigned int* raw  = (unsigned int*)sm;            // 16384 B
        unsigned int* ebuf = (unsigned int*)(sm + 16384);  // 16384 B
        int* cnt  = (int*)(sm + 32768);
        int* loff = (int*)(sm + 33792);
        int* lcur = (int*)(sm + 34816);
        int* cur  = (int*)(sm + 35840);
        int* wsum = (int*)(sm + 36864);
        cnt[tid] = 0;
        __syncthreads();
        const int base = blockIdx.x * EPB;
        const int mE = min(EPB, E_EDGES - base);           // %4 == 0
        const int nq = mE >> 2;
        for (int q = tid; q < nq; q += 256) {
            const int4 d4 = ((const int4*)(dstA + base))[q];
            const int4 s4 = ((const int4*)(srcA + base))[q];
            raw[4 * q + 0] = ((unsigned)d4.x << 16) | (unsigned)s4.x;
            raw[4 * q + 1] = ((unsigned)d4.y << 16) | (unsigned)s4.y;
            raw[4 * q + 2] = ((unsigned)d4.z << 16) | (unsigned)s4.z;
            raw[4 * q + 3] = ((unsigned)d4.w << 16) | (unsigned)s4.w;
            atomicAdd(&cnt[d4.x >> 8], 1);
            atomicAdd(&cnt[d4.y >> 8], 1);
            atomicAdd(&cnt[d4.z >> 8], 1);
            atomicAdd(&cnt[d4.w >> 8], 1);
        }
        __syncthreads();
        const int v = cnt[tid];
        const int excl = scan256_excl(v, wsum);
        loff[tid] = excl;
        lcur[tid] = excl;
        cur[tid] = (tid < NB && v > 0) ? (tid * CAP + atomicAdd(&gcur[tid], v)) : 0;
        __syncthreads();
        for (int p = tid; p < mE; p += 256) {
            const unsigned int u = raw[p];
            const int q = atomicAdd(&lcur[u >> 24], 1);
            ebuf[q] = u;
        }
        __syncthreads();
        for (int p = tid; p < mE; p += 256) {
            const unsigned int u = ebuf[p];
            const int b = (int)(u >> 24);
            binned[cur[b] + (p - loff[b])] = u;
        }
    } else {
        // ---- node1 role: xw1b = bf16(x @ W1), logits al_s/al_d ----
        float* sW  = (float*)sm;                 // 34*132*4 = 17952 B
        float* sx  = (float*)(sm + 17952);       // 32*36*4  = 4608 B
        float* sas = (float*)(sm + 22560);       // 512 B
        float* sad = (float*)(sm + 23072);       // 512 B -> 23584 total
        for (int i = tid; i < IN_CH * 128; i += 256) {
            int k = i >> 7, c = i & 127;
            sW[k * 132 + c] = W1[i];
        }
        if (tid < 128) { sas[tid] = a_src[tid]; sad[tid] = a_dst[tid]; }
        const int n0 = (blockIdx.x - NBB) * 32;
        for (int i = tid; i < 32 * IN_CH; i += 256) {
            int n = i / IN_CH;
            sx[n * 36 + (i - n * IN_CH)] = (n0 + n < N_NODES) ? x[n0 * IN_CH + i] : 0.f;
        }
        __syncthreads();

        const int tc = tid & 31, tn = tid >> 5;
        float acc[4][4] = {{0.f}};
        int k = 0;
        for (; k + 4 <= IN_CH; k += 4) {
            const float4 w0 = *reinterpret_cast<const float4*>(&sW[(k + 0) * 132 + 4 * tc]);
            const float4 w1 = *reinterpret_cast<const float4*>(&sW[(k + 1) * 132 + 4 * tc]);
            const float4 w2 = *reinterpret_cast<const float4*>(&sW[(k + 2) * 132 + 4 * tc]);
            const float4 w3 = *reinterpret_cast<const float4*>(&sW[(k + 3) * 132 + 4 * tc]);
            #pragma unroll
            for (int j = 0; j < 4; ++j) {
                const float4 h4 = *reinterpret_cast<const float4*>(&sx[(4 * tn + j) * 36 + k]);
                acc[j][0] += h4.x * w0.x + h4.y * w1.x + h4.z * w2.x + h4.w * w3.x;
                acc[j][1] += h4.x * w0.y + h4.y * w1.y + h4.z * w2.y + h4.w * w3.y;
                acc[j][2] += h4.x * w0.z + h4.y * w1.z + h4.z * w2.z + h4.w * w3.z;
                acc[j][3] += h4.x * w0.w + h4.y * w1.w + h4.z * w2.w + h4.w * w3.w;
            }
        }
        for (; k < IN_CH; ++k) {
            const float4 wv = *reinterpret_cast<const float4*>(&sW[k * 132 + 4 * tc]);
            #pragma unroll
            for (int j = 0; j < 4; ++j) {
                const float hj = sx[(4 * tn + j) * 36 + k];
                acc[j][0] += hj * wv.x; acc[j][1] += hj * wv.y;
                acc[j][2] += hj * wv.z; acc[j][3] += hj * wv.w;
            }
        }
        #pragma unroll
        for (int j = 0; j < 4; ++j) {
            const int node = n0 + 4 * tn + j;
            float ps = 0.f, pd = 0.f;
            #pragma unroll
            for (int c = 0; c < 4; ++c) {
                ps += acc[j][c] * sas[4 * tc + c];
                pd += acc[j][c] * sad[4 * tc + c];
            }
            #pragma unroll
            for (int off = 1; off < 16; off <<= 1) {
                ps += __shfl_xor(ps, off);
                pd += __shfl_xor(pd, off);
            }
            if (node < N_NODES) {
                if ((tc & 15) == 0) {
                    int h = tc >> 4;
                    al_s[node * 2 + h] = ps;
                    al_d[node * 2 + h] = pd;
                }
                ushort4 u;
                u.x = f2bf(acc[j][0]); u.y = f2bf(acc[j][1]);
                u.z = f2bf(acc[j][2]); u.w = f2bf(acc[j][3]);
                *reinterpret_cast<ushort4*>(&xw1b[node * 128 + 4 * tc]) = u;
            }
        }
    }
}

// ---------------------------------------------------------------------------
// Per-bucket fine sort (LDS-staged) -> sorted_src + rowspan.
// 1024 threads (16 waves, 4/SIMD) hide the LDS-atomic latency chains.
// ---------------------------------------------------------------------------
__global__ __launch_bounds__(1024) void k_fine(
    const int* __restrict__ gcur, const unsigned int* __restrict__ binned,
    int2* __restrict__ rowspan, int* __restrict__ sorted_src)
{
    __shared__ unsigned int sbin[CAP];    // 40 KB
    __shared__ int cnt[256], lcur[256];
    __shared__ int wsum[4];
    const int tid = threadIdx.x;
    const int b = blockIdx.x;
    const int bbase = b * CAP;
    const int cntb = gcur[b];
    if (tid < 256) cnt[tid] = 0;
    __syncthreads();
    for (int p = tid; p < cntb; p += 1024) {
        const unsigned int u = binned[bbase + p];
        sbin[p] = u;
        atomicAdd(&cnt[(u >> 16) & 255], 1);
    }
    __syncthreads();
    const int v = (tid < 256) ? cnt[tid] : 0;
    const int excl = scan256_1024(v, wsum);
    if (tid < 256) {
        lcur[tid] = excl;
        const int node = b * 256 + tid;
        if (node < N_NODES) rowspan[node] = make_int2(bbase + excl, bbase + excl + v);
    }
    __syncthreads();
    for (int p = tid; p < cntb; p += 1024) {
        const unsigned int u = sbin[p];
        const int q = atomicAdd(&lcur[(u >> 16) & 255], 1);
        sorted_src[bbase + q] = (int)(u & 0xffffu);
    }
}

// ---------------------------------------------------------------------------
// Layer 1 gather: one wave per node; lane owns cols 2l,2l+1 (one uint/row).
// Per-head (offset,weight) pair-packed LDS arrays -> one ds_read_b128 per
// edge pair, no per-edge selects. fv2 accumulators (packed f32 fma).
// ---------------------------------------------------------------------------
__global__ __launch_bounds__(256) void k_gather1(
    const int2* __restrict__ rowspan, const int* __restrict__ sorted_src,
    const unsigned int* __restrict__ xw1u,    // 64 uints per row
    const float* __restrict__ al_s, const float* __restrict__ al_d,
    const float* __restrict__ b1, float* __restrict__ hbuf)
{
    __shared__ float4 AB[2][4][32];           // [head][wave][pair]=(offA,wA,offB,wB)
    const int wave = threadIdx.x >> 6;
    const int lane = threadIdx.x & 63;
    const int node = (blockIdx.x * 256 + threadIdx.x) >> 6;
    if (node >= N_NODES) return;
    const int2 span = rowspan[node];
    const int head = lane >> 5;

    const float2 ald  = *reinterpret_cast<const float2*>(&al_d[node * 2]);
    const float2 als0 = *reinterpret_cast<const float2*>(&al_s[node * 2]);
    const float w0h0 = lrelu_exp(als0.x + ald.x);
    const float w0h1 = lrelu_exp(als0.y + ald.y);
    const float wself = head ? w0h1 : w0h0;

    const unsigned int su = xw1u[node * 64 + lane];
    fv2 accX = { wself * bflo(su), wself * bfhi(su) };
    fv2 accY = { 0.f, 0.f };
    float dv0 = 0.f, dv1 = 0.f;
    const float4* ABh = AB[head][wave];

    for (int base = span.x; base < span.y; base += 64) {
        const int rem = span.y - base;
        const int m = rem < 64 ? rem : 64;
        const int mp = (m + 1) & ~1;
        if (lane < m) {
            const int s = sorted_src[base + lane];
            const float2 als = *reinterpret_cast<const float2*>(&al_s[s * 2]);
            const float w0 = lrelu_exp(als.x + ald.x);
            const float w1 = lrelu_exp(als.y + ald.y);
            dv0 += w0; dv1 += w1;
            const float offf = __int_as_float(s << 6);
            ((float2*)&AB[0][wave][lane >> 1])[lane & 1] = make_float2(offf, w0);
            ((float2*)&AB[1][wave][lane >> 1])[lane & 1] = make_float2(offf, w1);
        } else if (lane < mp) {
            const float offf = __int_as_float(node << 6);
            ((float2*)&AB[0][wave][lane >> 1])[lane & 1] = make_float2(offf, 0.f);
            ((float2*)&AB[1][wave][lane >> 1])[lane & 1] = make_float2(offf, 0.f);
        }
        const int P = mp >> 1;
        int p = 0;
        for (; p + 4 <= P; p += 4) {
            const float4 q0 = ABh[p + 0];
            const float4 q1 = ABh[p + 1];
            const float4 q2 = ABh[p + 2];
            const float4 q3 = ABh[p + 3];
            const unsigned int a0 = xw1u[__float_as_int(q0.x) + lane];
            const unsigned int b0 = xw1u[__float_as_int(q0.z) + lane];
            const unsigned int a1 = xw1u[__float_as_int(q1.x) + lane];
            const unsigned int b1v = xw1u[__float_as_int(q1.z) + lane];
            const unsigned int a2 = xw1u[__float_as_int(q2.x) + lane];
            const unsigned int b2 = xw1u[__float_as_int(q2.z) + lane];
            const unsigned int a3 = xw1u[__float_as_int(q3.x) + lane];
            const unsigned int b3 = xw1u[__float_as_int(q3.z) + lane];
            fv2 f;
            f.x = bflo(a0); f.y = bfhi(a0); accX += f * q0.y;
            f.x = bflo(b0); f.y = bfhi(b0); accY += f * q0.w;
            f.x = bflo(a1); f.y = bfhi(a1); accX += f * q1.y;
            f.x = bflo(b1v); f.y = bfhi(b1v); accY += f * q1.w;
            f.x = bflo(a2); f.y = bfhi(a2); accX += f * q2.y;
            f.x = bflo(b2); f.y = bfhi(b2); accY += f * q2.w;
            f.x = bflo(a3); f.y = bfhi(a3); accX += f * q3.y;
            f.x = bflo(b3); f.y = bfhi(b3); accY += f * q3.w;
        }
        for (; p < P; ++p) {
            const float4 q = ABh[p];
            const unsigned int a = xw1u[__float_as_int(q.x) + lane];
            const unsigned int b = xw1u[__float_as_int(q.z) + lane];
            fv2 f;
            f.x = bflo(a); f.y = bfhi(a); accX += f * q.y;
            f.x = bflo(b); f.y = bfhi(b); accY += f * q.w;
        }
    }
    accX += accY;
    #pragma unroll
    for (int off = 32; off; off >>= 1) {
        dv0 += __shfl_xor(dv0, off);
        dv1 += __shfl_xor(dv1, off);
    }
    const float den = head ? (dv1 + w0h1) : (dv0 + w0h0);
    const float2 bv = *reinterpret_cast<const float2*>(&b1[2 * lane]);
    float o0 = accX.x / den + bv.x;
    float o1 = accX.y / den + bv.y;
    o0 = o0 > 0.f ? o0 : 0.f;
    o1 = o1 > 0.f ? o1 : 0.f;
    *reinterpret_cast<float2*>(&hbuf[node * 128 + 2 * lane]) = make_float2(o0, o1);
}

// ---------------------------------------------------------------------------
// Layer 2 node pre-pass (register-tiled): xw2b = bf16(h @ W2) [N,64].
// sh padded to stride 132 (16B-aligned rows) -> float4 reads over k,
// replacing 4 scalar ds_read_b32 per k with 1 ds_read_b128 per 4k.
// ---------------------------------------------------------------------------
__global__ __launch_bounds__(256) void k_node2(
    const float* __restrict__ hbuf, const float* __restrict__ W2,
    const float* __restrict__ a_src, const float* __restrict__ a_dst,
    unsigned short* __restrict__ xw2b, float* __restrict__ al_s, float* __restrict__ al_d)
{
    __shared__ __align__(16) float sW[128 * 64];
    __shared__ __align__(16) float sh[64 * 132];
    __shared__ float sas[64], sad[64];
    const int tid = threadIdx.x;
    for (int i = tid; i < 128 * 64; i += 256) sW[i] = W2[i];
    if (tid < 64) { sas[tid] = a_src[tid]; sad[tid] = a_dst[tid]; }
    const int n0 = blockIdx.x * 64;
    for (int i = tid; i < 64 * 32; i += 256) {
        const int n = i >> 5, c4 = i & 31;
        float4 v = make_float4(0.f, 0.f, 0.f, 0.f);
        if (n0 + n < N_NODES)
            v = reinterpret_cast<const float4*>(&hbuf[(long)(n0 + n) * 128])[c4];
        *reinterpret_cast<float4*>(&sh[n * 132 + 4 * c4]) = v;
    }
    __syncthreads();

    const int tc = tid & 15, tn = tid >> 4;
    float acc[4][4] = {{0.f}};
    for (int k = 0; k < 128; k += 4) {
        const float4 w0 = *reinterpret_cast<const float4*>(&sW[(k + 0) * 64 + 4 * tc]);
        const float4 w1 = *reinterpret_cast<const float4*>(&sW[(k + 1) * 64 + 4 * tc]);
        const float4 w2 = *reinterpret_cast<const float4*>(&sW[(k + 2) * 64 + 4 * tc]);
        const float4 w3 = *reinterpret_cast<const float4*>(&sW[(k + 3) * 64 + 4 * tc]);
        #pragma unroll
        for (int j = 0; j < 4; ++j) {
            const float4 h4 = *reinterpret_cast<const float4*>(&sh[(4 * tn + j) * 132 + k]);
            acc[j][0] += h4.x * w0.x + h4.y * w1.x + h4.z * w2.x + h4.w * w3.x;
            acc[j][1] += h4.x * w0.y + h4.y * w1.y + h4.z * w2.y + h4.w * w3.y;
            acc[j][2] += h4.x * w0.z + h4.y * w1.z + h4.z * w2.z + h4.w * w3.z;
            acc[j][3] += h4.x * w0.w + h4.y * w1.w + h4.z * w2.w + h4.w * w3.w;
        }
    }
    #pragma unroll
    for (int j = 0; j < 4; ++j) {
        const int node = n0 + 4 * tn + j;
        float ps = 0.f, pd = 0.f;
        #pragma unroll
        for (int c = 0; c < 4; ++c) {
            ps += acc[j][c] * sas[4 * tc + c];
            pd += acc[j][c] * sad[4 * tc + c];
        }
        #pragma unroll
        for (int off = 1; off < 16; off <<= 1) {
            ps += __shfl_xor(ps, off);
            pd += __shfl_xor(pd, off);
        }
        if (node < N_NODES) {
            if (tc == 0) { al_s[node] = ps; al_d[node] = pd; }
            ushort4 u;
            u.x = f2bf(acc[j][0]); u.y = f2bf(acc[j][1]);
            u.z = f2bf(acc[j][2]); u.w = f2bf(acc[j][3]);
            *reinterpret_cast<ushort4*>(&xw2b[node * 64 + 4 * tc]) = u;
        }
    }
}

// ---------------------------------------------------------------------------
// Layer 2 gather: half-wave per edge pair (4 edges/step), pair-packed
// (offset,weight) LDS, fv2 accumulators. out = acc/den + b2.
// ---------------------------------------------------------------------------
__global__ __launch_bounds__(256) void k_gather2(
    const int2* __restrict__ rowspan, const int* __restrict__ sorted_src,
    const unsigned int* __restrict__ xw2u,    // 32 uints per row
    const float* __restrict__ al_s, const float* __restrict__ al_d,
    const float* __restrict__ b2, float* __restrict__ out)
{
    __shared__ float4 AB[4][32];              // [wave][pair]=(offA,wA,offB,wB)
    const int wave = threadIdx.x >> 6;
    const int lane = threadIdx.x & 63;
    const int node = (blockIdx.x * 256 + threadIdx.x) >> 6;
    if (node >= N_NODES) return;
    const int2 span = rowspan[node];
    const int li = lane & 31, hsel = lane >> 5;

    const float ald = al_d[node];
    const float w0s = lrelu_exp(al_s[node] + ald);
    const unsigned int su = xw2u[node * 32 + li];
    const float wself = hsel ? 0.f : w0s;
    fv2 acc = { wself * bflo(su), wself * bfhi(su) };
    float dv = 0.f;
    const float4* ABw = AB[wave];

    for (int base = span.x; base < span.y; base += 64) {
        const int rem = span.y - base;
        const int m = rem < 64 ? rem : 64;
        const int mp = (m + 3) & ~3;
        if (lane < m) {
            const int s = sorted_src[base + lane];
            const float w = lrelu_exp(al_s[s] + ald);
            dv += w;
            ((float2*)&AB[wave][lane >> 1])[lane & 1] =
                make_float2(__int_as_float(s << 5), w);
        } else if (lane < mp) {
            ((float2*)&AB[wave][lane >> 1])[lane & 1] =
                make_float2(__int_as_float(node << 5), 0.f);
        }
        const int P = mp >> 1;                // even
        int p = hsel;
        for (; p + 2 < P; p += 4) {
            const float4 qA = ABw[p];
            const float4 qB = ABw[p + 2];
            const unsigned int aA = xw2u[__float_as_int(qA.x) + li];
            const unsigned int bA = xw2u[__float_as_int(qA.z) + li];
            const unsigned int aB = xw2u[__float_as_int(qB.x) + li];
            const unsigned int bB = xw2u[__float_as_int(qB.z) + li];
            fv2 f;
            f.x = bflo(aA); f.y = bfhi(aA); acc += f * qA.y;
            f.x = bflo(bA); f.y = bfhi(bA); acc += f * qA.w;
            f.x = bflo(aB); f.y = bfhi(aB); acc += f * qB.y;
            f.x = bflo(bB); f.y = bfhi(bB); acc += f * qB.w;
        }
        for (; p < P; p += 2) {
            const float4 q = ABw[p];
            const unsigned int a = xw2u[__float_as_int(q.x) + li];
            const unsigned int b = xw2u[__float_as_int(q.z) + li];
            fv2 f;
            f.x = bflo(a); f.y = bfhi(a); acc += f * q.y;
            f.x = bflo(b); f.y = bfhi(b); acc += f * q.w;
        }
    }
    acc.x += __shfl_xor(acc.x, 32);
    acc.y += __shfl_xor(acc.y, 32);
    #pragma unroll
    for (int off = 32; off; off >>= 1) dv += __shfl_xor(dv, off);
    if (lane < 32) {
        const float den = dv + w0s;
        const float2 bv = *reinterpret_cast<const float2*>(&b2[2 * li]);
        *reinterpret_cast<float2*>(&out[node * 64 + 2 * li]) =
            make_float2(acc.x / den + bv.x, acc.y / den + bv.y);
    }
}

extern "C" void kernel_launch(void* const* d_in, const int* in_sizes, int n_in,
                              void* d_out, int out_size, void* d_ws, size_t ws_size,
                              hipStream_t stream)
{
    const float* x   = (const float*)d_in[0];
    const int*   ei  = (const int*)d_in[1];
    const float* W1  = (const float*)d_in[2];
    const float* as1 = (const float*)d_in[3];
    const float* ad1 = (const float*)d_in[4];
    const float* b1  = (const float*)d_in[5];
    const float* W2  = (const float*)d_in[6];
    const float* as2 = (const float*)d_in[7];
    const float* ad2 = (const float*)d_in[8];
    const float* b2  = (const float*)d_in[9];
    float* out = (float*)d_out;

    const int* srcA = ei;
    const int* dstA = ei + E_EDGES;

    // Workspace layout (bytes). Total 54,251,648 B.
    char* ws = (char*)d_ws;
    int2*  rowspan    = (int2*)(ws);                         // 400 KB (pad 409,600)
    int*   sorted_src = (int*)(ws + 409600);                 // 7.84 MB
    int*   gcur       = (int*)(ws + 8249600);                // NB ints (pad 2 KB)
    float* al_s1      = (float*)(ws + 8251648);              // 400 KB
    float* al_d1      = (float*)(ws + 8651648);              // 400 KB
    float* al_s2      = (float*)(ws + 9051648);              // 200 KB
    float* al_d2      = (float*)(ws + 9251648);              // 200 KB
    unsigned short* xw1b = (unsigned short*)(ws + 9451648);  // 12.8 MB bf16
    float* hbuf       = (float*)(ws + 22251648);             // 25.6 MB fp32
    unsigned int* binned = (unsigned int*)hbuf;              // alias: dead before gather1
    unsigned short* xw2b = (unsigned short*)(ws + 47851648); // 6.4 MB bf16

    hipMemsetAsync(gcur, 0, NB * sizeof(int), stream);
    hipLaunchKernelGGL(k_bin_node1, dim3(NBB + (N_NODES + 31) / 32), dim3(256), 0, stream,
                       srcA, dstA, gcur, binned,
                       x, W1, as1, ad1, xw1b, al_s1, al_d1);
    hipLaunchKernelGGL(k_fine, dim3(NB), dim3(1024), 0, stream,
                       gcur, binned, rowspan, sorted_src);
    hipLaunchKernelGGL(k_gather1, dim3((N_NODES + 3) / 4), dim3(256), 0, stream,
                       rowspan, sorted_src, (const unsigned int*)xw1b,
                       al_s1, al_d1, b1, hbuf);
    hipLaunchKernelGGL(k_node2, dim3((N_NODES + 63) / 64), dim3(256), 0, stream,
                       hbuf, W2, as2, ad2, xw2b, al_s2, al_d2);
    hipLaunchKernelGGL(k_gather2, dim3((N_NODES + 3) / 4), dim3(256), 0, stream,
                       rowspan, sorted_src, (const unsigned int*)xw2b,
                       al_s2, al_d2, b2, out);
}